// Round 11
// baseline (2183.357 us; speedup 1.0000x reference)
//
#include <hip/hip_runtime.h>
#include <hip/hip_bf16.h>
#include <math.h>

// Fixed problem dims
static constexpr int nB = 8, nT = 512, nE = 1024, nL = 8, nD = 512;
static constexpr int nBT = nB * nT;   // 4096 rows (b,t)
static constexpr int nLD = nL * nD;   // 4096

typedef __attribute__((ext_vector_type(8))) short short8v;  // 8 bf16 (4 VGPRs)
typedef __attribute__((ext_vector_type(4))) float f32x4;
typedef __attribute__((ext_vector_type(4))) unsigned int u32x4;  // asm-safe

__device__ __forceinline__ unsigned short f2bf(float f) {
    unsigned int u = __float_as_uint(f);
    return (unsigned short)((u + 0x7fffu + ((u >> 16) & 1u)) >> 16);  // RNE
}
__device__ __forceinline__ float bfu2f(unsigned short u) {
    return __uint_as_float(((unsigned int)u) << 16);
}
__device__ __forceinline__ float gelu_f(float x) {
    return 0.5f * x * (1.0f + erff(x * 0.70710678118654752f));  // exact GELU
}

// dst[r] = sum_i src[r,i] * (w ? w[i] : 1)
__global__ __launch_bounds__(256) void k_wdot(const float* __restrict__ src,
                                              const float* __restrict__ w,
                                              float* __restrict__ dst,
                                              int rows, int rowlen) {
    int row = blockIdx.x * 4 + (threadIdx.x >> 6);
    if (row >= rows) return;
    int lane = threadIdx.x & 63;
    const float* p = src + (size_t)row * rowlen;
    float s = 0.f;
    if (w) { for (int i = lane; i < rowlen; i += 64) s += p[i] * w[i]; }
    else   { for (int i = lane; i < rowlen; i += 64) s += p[i]; }
#pragma unroll
    for (int off = 32; off > 0; off >>= 1) s += __shfl_down(s, off, 64);
    if (lane == 0) dst[row] = s;
}

// zero record tags in BOTH mirrors (LLC-visible; fast mirror healing is
// handled by the equality protocol, this is defensive for first launch)
__global__ __launch_bounds__(256) void k_init2(unsigned int* recsL, unsigned int* recsF) {
    int i = blockIdx.x * 256 + threadIdx.x;   // 16384 records
    if (i < 2 * nL * nB * 128) {
        __hip_atomic_store(recsL + i * 4 + 3, 0u,
                           __ATOMIC_RELAXED, __HIP_MEMORY_SCOPE_AGENT);
        __hip_atomic_store(recsF + i * 4 + 3, 0u,
                           __ATOMIC_RELAXED, __HIP_MEMORY_SCOPE_AGENT);
    }
}

// flat fp32 -> bf16 cast
__global__ __launch_bounds__(256) void k_cast(const float* __restrict__ s,
                                              unsigned short* __restrict__ d, int n) {
    int idx = (blockIdx.x * 256 + threadIdx.x) * 4;
    if (idx >= n) return;
    float4 v = *reinterpret_cast<const float4*>(s + idx);
    ushort4 o;
    o.x = f2bf(v.x); o.y = f2bf(v.y); o.z = f2bf(v.z); o.w = f2bf(v.w);
    *reinterpret_cast<ushort4*>(d + idx) = o;
}

// tiled transpose-cast: dst[c][r] (bf16) = src[r][c] (fp32); batch via z
__global__ __launch_bounds__(256) void k_transp(const float* __restrict__ src,
                                                unsigned short* __restrict__ dst,
                                                int R, int Cc,
                                                long long sSrc, long long sDst) {
    src += (size_t)blockIdx.z * sSrc;
    dst += (size_t)blockIdx.z * sDst;
    __shared__ float t[32][33];
    const int tx = threadIdx.x & 31, ty = threadIdx.x >> 5;  // ty 0..7
    const int r0 = blockIdx.y * 32, c0 = blockIdx.x * 32;
#pragma unroll
    for (int r = 0; r < 4; ++r)
        t[ty + r * 8][tx] = src[(size_t)(r0 + ty + r * 8) * Cc + c0 + tx];
    __syncthreads();
#pragma unroll
    for (int r = 0; r < 4; ++r)
        dst[(size_t)(c0 + ty + r * 8) * R + r0 + tx] = f2bf(t[tx][ty + r * 8]);
}

// Pack glu_w into MFMA B-fragment layout with INTERLEAVED a/g columns.
__global__ __launch_bounds__(256) void k_pack2(const float* __restrict__ src,
                                               uint4* __restrict__ dst) {
    const int blk = blockIdx.x;            // l*64 + q*8 + w   (512 blocks)
    const int w = blk & 7, q = (blk >> 3) & 7, l = blk >> 6;
    const float* wl = src + (size_t)l * nD * 1024;
    for (int i = threadIdx.x; i < 16 * 64; i += 256) {
        const int kt = i >> 6, ln = i & 63;
        const int j = ln & 15, g = ln >> 4;
        const int u = j >> 1;
        const int col = (j & 1) ? (512 + q * 64 + w * 8 + u)
                                : (q * 64 + w * 8 + u);
        const int k0 = 32 * kt + 8 * g;
        unsigned pr[4];
#pragma unroll
        for (int p = 0; p < 4; ++p) {
            float a = wl[(size_t)(k0 + 2 * p) * 1024 + col];
            float c = wl[(size_t)(k0 + 2 * p + 1) * 1024 + col];
            pr[p] = (unsigned)f2bf(a) | ((unsigned)f2bf(c) << 16);
        }
        dst[((((size_t)l * 8 + q) * 8 + w) * 16 + kt) * 64 + ln] =
            make_uint4(pr[0], pr[1], pr[2], pr[3]);
    }
}

// ---------------------------------------------------------------------------
// bf16 MFMA GEMM (unchanged from R9)
// ---------------------------------------------------------------------------
template<int ACT>
__global__ __launch_bounds__(256) void k_gemm_bf(
    const unsigned short* __restrict__ A, int lda, long long sA,
    const unsigned short* __restrict__ Bt, int ldb, long long sB,
    const float* __restrict__ bias, long long sBias,
    float* __restrict__ C, int ldc, long long sC,
    int M, int N, int K)
{
    A  += (size_t)blockIdx.z * sA;
    Bt += (size_t)blockIdx.z * sB;
    C  += (size_t)blockIdx.z * sC;
    const float* biasp = bias ? bias + (size_t)blockIdx.z * sBias : nullptr;

    __shared__ __align__(16) unsigned short A_s[128][40];
    __shared__ __align__(16) unsigned short B_s[128][40];
    const int tid = threadIdx.x, lane = tid & 63;
    const int wv = tid >> 6;
    const int wm = (wv >> 1) * 64, wn = (wv & 1) * 64;
    const int bm = blockIdx.y * 128, bn = blockIdx.x * 128;
    const int srow = tid >> 2, sc8 = (tid & 3) * 8;

    f32x4 acc[4][4];
#pragma unroll
    for (int i = 0; i < 4; ++i)
#pragma unroll
        for (int j = 0; j < 4; ++j) acc[i][j] = f32x4{0.f, 0.f, 0.f, 0.f};

    const int fr = lane & 15, fg = (lane >> 4) * 8;

    for (int kt = 0; kt < K; kt += 32) {
        uint4 a0 = *reinterpret_cast<const uint4*>(A + (size_t)(bm + srow) * lda + kt + sc8);
        uint4 a1 = *reinterpret_cast<const uint4*>(A + (size_t)(bm + srow + 64) * lda + kt + sc8);
        uint4 b0 = *reinterpret_cast<const uint4*>(Bt + (size_t)(bn + srow) * ldb + kt + sc8);
        uint4 b1 = *reinterpret_cast<const uint4*>(Bt + (size_t)(bn + srow + 64) * ldb + kt + sc8);
        __syncthreads();
        *reinterpret_cast<uint4*>(&A_s[srow][sc8]) = a0;
        *reinterpret_cast<uint4*>(&A_s[srow + 64][sc8]) = a1;
        *reinterpret_cast<uint4*>(&B_s[srow][sc8]) = b0;
        *reinterpret_cast<uint4*>(&B_s[srow + 64][sc8]) = b1;
        __syncthreads();
        short8v af[4], bf[4];
#pragma unroll
        for (int mi = 0; mi < 4; ++mi)
            af[mi] = *reinterpret_cast<const short8v*>(&A_s[wm + mi * 16 + fr][fg]);
#pragma unroll
        for (int ni = 0; ni < 4; ++ni)
            bf[ni] = *reinterpret_cast<const short8v*>(&B_s[wn + ni * 16 + fr][fg]);
#pragma unroll
        for (int mi = 0; mi < 4; ++mi)
#pragma unroll
            for (int ni = 0; ni < 4; ++ni)
                acc[mi][ni] = __builtin_amdgcn_mfma_f32_16x16x32_bf16(
                    af[mi], bf[ni], acc[mi][ni], 0, 0, 0);
    }

#pragma unroll
    for (int mi = 0; mi < 4; ++mi)
#pragma unroll
        for (int ni = 0; ni < 4; ++ni) {
            const int col = bn + wn + ni * 16 + (lane & 15);
            const float bv = biasp ? biasp[col] : 0.f;
#pragma unroll
            for (int p = 0; p < 4; ++p) {
                const int row = bm + wm + mi * 16 + (lane >> 4) * 4 + p;
                float v = acc[mi][ni][p] + bv;
                if (ACT == 1) v = gelu_f(v);
                C[(size_t)row * ldc + col] = v;
            }
        }
}

// ---------------------------------------------------------------------------
// Scan: tag-in-data exchange with DUAL-MIRROR publication.
// Producer stores each record twice: sc0-only (XCD-L2 "fast" mirror) and
// sc0 sc1 (LLC mirror, guaranteed visible -- the proven R9 protocol).
// Consumer waves poll the fast mirror (bounded tries), and fall back
// STICKILY to the LLC mirror on timeout. Correct under ANY XCD placement:
// a wrong co-location guess costs one bounded burn, never a deadlock.
// ---------------------------------------------------------------------------
__global__ __launch_bounds__(512, 1) void k_scan7(
    const float* __restrict__ tokens,      // [B,T,L,D]
    const uint4* __restrict__ wswz,        // packed B-fragments (interleaved)
    const float* __restrict__ glu_b,       // [L,2D]
    const float* __restrict__ sc_sum, const float* __restrict__ ii_sum,
    const float* __restrict__ ln_glu_g, const float* __restrict__ ln_glu_b,
    const float* __restrict__ ln_state_g, const float* __restrict__ ln_state_b,
    float* __restrict__ vout,              // [B,T,L,D] raw v (fp32, plain)
    unsigned int* __restrict__ recsL,      // LLC mirror
    unsigned int* __restrict__ recsF)      // fast (XCD-L2) mirror
{
    const int l = blockIdx.x & 7, q = blockIdx.x >> 3;
    const int tid = threadIdx.x, w = tid >> 6, lane = tid & 63;
    const int b = w;  // wave = batch

    __shared__ __align__(16) unsigned hn_pk[8][260];       // bf16 pairs, padded
    __shared__ __align__(16) unsigned zbuf[4];
    __shared__ __align__(16) unsigned short vrow[8][512];  // consumer v (bf16)
    __shared__ __align__(16) unsigned short vstage[8][64]; // producer stage
    __shared__ __align__(16) float vsq[8][8][2];           // [b][w]{S,Q}

    uint4 wr[16];
    {
        const uint4* wp = wswz + ((((size_t)l * 8 + q) * 8 + w) * 16) * 64 + lane;
#pragma unroll
        for (int kt = 0; kt < 16; ++kt) wr[kt] = wp[kt * 64];
    }
    const int d0 = lane * 8;
    float P_sc[8], P_ii[8], P_gg[8], P_gb[8], P_sg[8], P_sb[8];
#pragma unroll
    for (int j = 0; j < 8; j += 4) {
        *reinterpret_cast<float4*>(&P_sc[j]) = *reinterpret_cast<const float4*>(sc_sum + l * nD + d0 + j);
        *reinterpret_cast<float4*>(&P_ii[j]) = *reinterpret_cast<const float4*>(ii_sum + l * nD + d0 + j);
        *reinterpret_cast<float4*>(&P_gg[j]) = *reinterpret_cast<const float4*>(ln_glu_g + d0 + j);
        *reinterpret_cast<float4*>(&P_gb[j]) = *reinterpret_cast<const float4*>(ln_glu_b + d0 + j);
        *reinterpret_cast<float4*>(&P_sg[j]) = *reinterpret_cast<const float4*>(ln_state_g + d0 + j);
        *reinterpret_cast<float4*>(&P_sb[j]) = *reinterpret_cast<const float4*>(ln_state_b + d0 + j);
    }
    const int cu = (lane & 15) >> 1;
    const int mycol = (lane & 1) ? (512 + q * 64 + w * 8 + cu)
                                 : (q * 64 + w * 8 + cu);
    const float bias_c = glu_b[l * 1024 + mycol];
    const int vcol = q * 64 + w * 8 + cu;

    if (tid < 4) zbuf[tid] = 0u;

    const float* tokp = tokens + ((size_t)b * nT * nL + l) * nD + d0;

    const unsigned* afp; int astep;
    {
        int bb = lane & 15, g = lane >> 4;
        if (bb < 8) { afp = &hn_pk[bb][g * 4]; astep = 16; }
        else        { afp = &zbuf[0];          astep = 0;  }
    }
    __syncthreads();

    bool use_fast = true;   // per-wave sticky flag (uniform decisions only)

    float4 tk0 = *reinterpret_cast<const float4*>(tokp);
    float4 tk1 = *reinterpret_cast<const float4*>(tokp + 4);

    for (int t = 0; t < nT; ++t) {
        float tk[8] = {tk0.x, tk0.y, tk0.z, tk0.w, tk1.x, tk1.y, tk1.z, tk1.w};
        float h[8];
        if (t > 0) {
            const size_t roff = ((((size_t)((t - 1) & 1) * nL + l) * nB + b) * 128) * 4;
            u32x4 ra, rb;
            int ok = 0;
            if (use_fast) {
                const unsigned* pa = recsF + roff + lane * 4;
                const unsigned* pb = recsF + roff + (lane + 64) * 4;
                int tries = 0;
                do {
                    asm volatile(
                        "global_load_dwordx4 %0, %2, off sc0\n\t"
                        "global_load_dwordx4 %1, %3, off sc0\n\t"
                        "s_waitcnt vmcnt(0)"
                        : "=&v"(ra), "=&v"(rb)
                        : "v"(pa), "v"(pb)
                        : "memory");
                    ok = (ra[3] == (unsigned)t) && (rb[3] == (unsigned)t);
                    ++tries;
                } while (!__all(ok) && tries < 256);
                if (!__all(ok)) use_fast = false;  // sticky fallback, no deadlock
            }
            if (!use_fast) {
                const unsigned* pa = recsL + roff + lane * 4;
                const unsigned* pb = recsL + roff + (lane + 64) * 4;
                do {
                    asm volatile(
                        "global_load_dwordx4 %0, %2, off sc0 sc1\n\t"
                        "global_load_dwordx4 %1, %3, off sc0 sc1\n\t"
                        "s_waitcnt vmcnt(0)"
                        : "=&v"(ra), "=&v"(rb)
                        : "v"(pa), "v"(pb)
                        : "memory");
                    ok = (ra[3] == (unsigned)t) && (rb[3] == (unsigned)t);
                } while (!__all(ok));
            }

            // embedded LN stats (odd lanes carry j=1 records with S,Q)
            float S = 0.f, Q = 0.f;
            if (lane & 1) {
                S = __uint_as_float(ra[1]) + __uint_as_float(rb[1]);
                Q = __uint_as_float(ra[2]) + __uint_as_float(rb[2]);
            }
#pragma unroll
            for (int o = 32; o > 0; o >>= 1) { S += __shfl_xor(S, o, 64); Q += __shfl_xor(Q, o, 64); }
            const float mv = S * (1.f / nD);
            const float iv = rsqrtf(Q * (1.f / nD) - mv * mv + 1e-5f);

            // redistribute payloads into vrow[b] (wave-local LDS region)
            {
                const int ia = lane, ib2 = lane + 64;
                const int qa = ia >> 4, wa = (ia >> 1) & 7, ja = ia & 1;
                const int qb2 = ib2 >> 4, wb2 = (ib2 >> 1) & 7;
                unsigned* da = reinterpret_cast<unsigned*>(&vrow[b][qa * 64 + wa * 8 + ja * 6]);
                unsigned* db = reinterpret_cast<unsigned*>(&vrow[b][qb2 * 64 + wb2 * 8 + ja * 6]);
                if (!ja) {
                    da[0] = ra[0]; da[1] = ra[1]; da[2] = ra[2];
                    db[0] = rb[0]; db[1] = rb[1]; db[2] = rb[2];
                } else {
                    da[0] = ra[0];
                    db[0] = rb[0];
                }
            }
            asm volatile("s_waitcnt lgkmcnt(0)" ::: "memory");
            __builtin_amdgcn_sched_barrier(0);
            uint4 pv = *reinterpret_cast<const uint4*>(&vrow[b][lane * 8]);
            float vv[8];
            vv[0] = bfu2f((unsigned short)(pv.x & 0xffffu));
            vv[1] = bfu2f((unsigned short)(pv.x >> 16));
            vv[2] = bfu2f((unsigned short)(pv.y & 0xffffu));
            vv[3] = bfu2f((unsigned short)(pv.y >> 16));
            vv[4] = bfu2f((unsigned short)(pv.z & 0xffffu));
            vv[5] = bfu2f((unsigned short)(pv.z >> 16));
            vv[6] = bfu2f((unsigned short)(pv.w & 0xffffu));
            vv[7] = bfu2f((unsigned short)(pv.w >> 16));
#pragma unroll
            for (int j = 0; j < 8; ++j) {
                float st = (vv[j] - mv) * iv * P_sg[j] + P_sb[j];
                h[j] = st * P_sc[j] + tk[j] * P_ii[j];
            }
        } else {
#pragma unroll
            for (int j = 0; j < 8; ++j) h[j] = tk[j] * P_ii[j];
        }

        // token prefetch for t+1 (in flight across barriers)
        if (t + 1 < nT) {
            tk0 = *reinterpret_cast<const float4*>(tokp + (size_t)(t + 1) * nLD);
            tk1 = *reinterpret_cast<const float4*>(tokp + (size_t)(t + 1) * nLD + 4);
        }

        // LN(h) over the wave's 512 dims
        float S = 0.f, Q = 0.f;
#pragma unroll
        for (int j = 0; j < 8; ++j) { S += h[j]; Q += h[j] * h[j]; }
#pragma unroll
        for (int o = 32; o > 0; o >>= 1) { S += __shfl_xor(S, o, 64); Q += __shfl_xor(Q, o, 64); }
        const float mh = S * (1.f / nD);
        const float ih = rsqrtf(Q * (1.f / nD) - mh * mh + 1e-5f);
        unsigned pr[4];
#pragma unroll
        for (int p = 0; p < 4; ++p) {
            float a0 = (h[2 * p]     - mh) * ih * P_gg[2 * p]     + P_gb[2 * p];
            float a1 = (h[2 * p + 1] - mh) * ih * P_gg[2 * p + 1] + P_gb[2 * p + 1];
            pr[p] = (unsigned)f2bf(a0) | ((unsigned)f2bf(a1) << 16);
        }
        *reinterpret_cast<uint4*>(&hn_pk[b][lane * 4]) = make_uint4(pr[0], pr[1], pr[2], pr[3]);

        // BAR1: hn ready (LDS only)
        asm volatile("s_waitcnt lgkmcnt(0)" ::: "memory");
        __builtin_amdgcn_s_barrier();
        __builtin_amdgcn_sched_barrier(0);

        // MFMA: rows = batches, cols = wave's interleaved 16-col tile
        f32x4 acc0 = {0.f, 0.f, 0.f, 0.f}, acc1 = {0.f, 0.f, 0.f, 0.f};
#pragma unroll
        for (int kt = 0; kt < 8; ++kt) {
            short8v a0 = *reinterpret_cast<const short8v*>(afp + (2 * kt) * astep);
            short8v a1 = *reinterpret_cast<const short8v*>(afp + (2 * kt + 1) * astep);
            acc0 = __builtin_amdgcn_mfma_f32_16x16x32_bf16(
                a0, __builtin_bit_cast(short8v, wr[2 * kt]), acc0, 0, 0, 0);
            acc1 = __builtin_amdgcn_mfma_f32_16x16x32_bf16(
                a1, __builtin_bit_cast(short8v, wr[2 * kt + 1]), acc1, 0, 0, 0);
        }

        // GLU in-register; v to vout (plain fp32) + vstage (bf16) + partials
        float x[4], y[4];
#pragma unroll
        for (int i = 0; i < 4; ++i) x[i] = acc0[i] + acc1[i] + bias_c;
#pragma unroll
        for (int i = 0; i < 4; ++i) y[i] = __shfl_xor(x[i], 1, 64);
        float sv[4], sq[4];
        const int r0 = (lane >> 4) * 4;
        const bool prod = (lane < 32) && !(lane & 1);
#pragma unroll
        for (int i = 0; i < 4; ++i) {
            float v = x[i] / (1.f + __expf(-y[i]));
            sv[i] = prod ? v : 0.f;
            sq[i] = prod ? v * v : 0.f;
            if (prod) {
                vout[(((size_t)(r0 + i) * nT + t) * nL + l) * nD + vcol] = v;
                vstage[r0 + i][w * 8 + cu] = f2bf(v);
            }
        }
#pragma unroll
        for (int i = 0; i < 4; ++i) {
            sv[i] += __shfl_xor(sv[i], 2, 64); sq[i] += __shfl_xor(sq[i], 2, 64);
            sv[i] += __shfl_xor(sv[i], 4, 64); sq[i] += __shfl_xor(sq[i], 4, 64);
            sv[i] += __shfl_xor(sv[i], 8, 64); sq[i] += __shfl_xor(sq[i], 8, 64);
        }
        if (lane == 0 || lane == 16) {
#pragma unroll
            for (int i = 0; i < 4; ++i) {
                vsq[r0 + i][w][0] = sv[i];
                vsq[r0 + i][w][1] = sq[i];
            }
        }

        // BAR2: vstage/vsq visible (LDS only; vout stores stay in flight)
        asm volatile("s_waitcnt lgkmcnt(0)" ::: "memory");
        __builtin_amdgcn_s_barrier();
        __builtin_amdgcn_sched_barrier(0);

        // builders: 128 threads emit records {payload, tag=t+1} to BOTH mirrors
        if (tid < 128) {
            const int bb = tid >> 4, wb = (tid >> 1) & 7, jb = tid & 1;
            const unsigned* vp = reinterpret_cast<const unsigned*>(&vstage[bb][wb * 8]);
            u32x4 rec;
            if (!jb) { rec[0] = vp[0]; rec[1] = vp[1]; rec[2] = vp[2]; }
            else {
                rec[0] = vp[3];
                rec[1] = __float_as_uint(vsq[bb][wb][0]);
                rec[2] = __float_as_uint(vsq[bb][wb][1]);
            }
            rec[3] = (unsigned)(t + 1);
            const size_t ridx = (((((size_t)(t & 1) * nL + l) * nB + bb) * 128)
                                 + q * 16 + wb * 2 + jb) * 4;
            unsigned* dstF = recsF + ridx;
            unsigned* dstL = recsL + ridx;
            asm volatile("global_store_dwordx4 %0, %1, off sc0"
                         :: "v"(dstF), "v"(rec) : "memory");
            asm volatile("global_store_dwordx4 %0, %1, off sc0 sc1"
                         :: "v"(dstL), "v"(rec) : "memory");
        }
        // no drain: tag rides with payload; next poll provides the sync
    }
}

// y = LN_ff( LN_state(raw v) * os_sum[l] ); OUTPUT bf16 (feeds MFMA ff1 GEMM)
__global__ __launch_bounds__(256) void k_y2(
    const float* __restrict__ vout, const float* __restrict__ os_sum,
    const float* __restrict__ lsg, const float* __restrict__ lsb,
    const float* __restrict__ fg, const float* __restrict__ fb,
    unsigned short* __restrict__ y)
{
    const int row = blockIdx.x * 4 + (threadIdx.x >> 6);   // over B*T*L
    const int lane = threadIdx.x & 63;
    const int l = row & 7;

    const float* vp = vout + (size_t)row * nD;
    const int base = lane * 8;
    float vv[8];
    *reinterpret_cast<float4*>(&vv[0]) = *reinterpret_cast<const float4*>(vp + base);
    *reinterpret_cast<float4*>(&vv[4]) = *reinterpret_cast<const float4*>(vp + base + 4);
    float S = 0.f, Q = 0.f;
#pragma unroll
    for (int j = 0; j < 8; ++j) { S += vv[j]; Q += vv[j] * vv[j]; }
#pragma unroll
    for (int o = 32; o > 0; o >>= 1) { S += __shfl_xor(S, o, 64); Q += __shfl_xor(Q, o, 64); }
    const float mv = S * (1.f / nD);
    const float iv = rsqrtf(Q * (1.f / nD) - mv * mv + 1e-5f);

    const float* op = os_sum + l * nD;
    float val[8];
    float s2 = 0.f, q2 = 0.f;
#pragma unroll
    for (int j = 0; j < 8; j += 4) {
        float4 o4 = *reinterpret_cast<const float4*>(op + base + j);
        float4 g4 = *reinterpret_cast<const float4*>(lsg + base + j);
        float4 b4 = *reinterpret_cast<const float4*>(lsb + base + j);
        val[j]     = ((vv[j]     - mv) * iv * g4.x + b4.x) * o4.x;
        val[j + 1] = ((vv[j + 1] - mv) * iv * g4.y + b4.y) * o4.y;
        val[j + 2] = ((vv[j + 2] - mv) * iv * g4.z + b4.z) * o4.z;
        val[j + 3] = ((vv[j + 3] - mv) * iv * g4.w + b4.w) * o4.w;
    }
#pragma unroll
    for (int j = 0; j < 8; ++j) { s2 += val[j]; q2 += val[j] * val[j]; }
#pragma unroll
    for (int o = 32; o > 0; o >>= 1) { s2 += __shfl_xor(s2, o, 64); q2 += __shfl_xor(q2, o, 64); }
    const float m2 = s2 * (1.f / nD);
    const float i2 = rsqrtf(q2 * (1.f / nD) - m2 * m2 + 1e-5f);
    const float* gp = fg + l * nD;
    const float* bp = fb + l * nD;
    unsigned short* yp = y + (size_t)row * nD;
    unsigned pk[4];
#pragma unroll
    for (int j = 0; j < 8; j += 4) {
        float4 g4 = *reinterpret_cast<const float4*>(gp + base + j);
        float4 b4 = *reinterpret_cast<const float4*>(bp + base + j);
        float o0 = (val[j]     - m2) * i2 * g4.x + b4.x;
        float o1 = (val[j + 1] - m2) * i2 * g4.y + b4.y;
        float o2 = (val[j + 2] - m2) * i2 * g4.z + b4.z;
        float o3 = (val[j + 3] - m2) * i2 * g4.w + b4.w;
        pk[j / 4 * 2]     = (unsigned)f2bf(o0) | ((unsigned)f2bf(o1) << 16);
        pk[j / 4 * 2 + 1] = (unsigned)f2bf(o2) | ((unsigned)f2bf(o3) << 16);
    }
    *reinterpret_cast<uint4*>(yp + base) = make_uint4(pk[0], pk[1], pk[2], pk[3]);
}

// scores from h via w2a; softmax over L; write scaled h as bf16; store probs
__global__ __launch_bounds__(256) void k_scores(
    const float* __restrict__ h, const float* __restrict__ w2a,
    const float* __restrict__ c2, const float* __restrict__ attn_b,
    unsigned short* __restrict__ hbf, float* __restrict__ scores)
{
    const int bt = blockIdx.x;
    const int tid = threadIdx.x, wid = tid >> 6, lane = tid & 63;
    __shared__ float slog[nL];
    const float* hrow = h + (size_t)bt * nLD;
    for (int l = wid; l < nL; l += 4) {
        const float* hp = hrow + l * nD;
        const float* wp = w2a + l * nD;
        float s = 0.f;
        for (int i = lane; i < nD; i += 64) s += hp[i] * wp[i];
#pragma unroll
        for (int off = 32; off > 0; off >>= 1) s += __shfl_down(s, off, 64);
        if (lane == 0) slog[l] = s + c2[l] + attn_b[0];
    }
    __syncthreads();
    float mx = -1e30f;
#pragma unroll
    for (int l = 0; l < nL; ++l) mx = fmaxf(mx, slog[l]);
    float den = 0.f;
#pragma unroll
    for (int l = 0; l < nL; ++l) den += __expf(slog[l] - mx);
    float rden = 1.f / den;
    unsigned short* obase = hbf + (size_t)bt * nLD;
#pragma unroll
    for (int it = 0; it < 4; ++it) {
        int idx = tid * 4 + it * 1024;
        int l = idx >> 9;
        float s = __expf(slog[l] - mx) * rden;
        float4 v = *reinterpret_cast<const float4*>(hrow + idx);
        unsigned p0 = (unsigned)f2bf(v.x * s) | ((unsigned)f2bf(v.y * s) << 16);
        unsigned p1 = (unsigned)f2bf(v.z * s) | ((unsigned)f2bf(v.w * s) << 16);
        *reinterpret_cast<uint2*>(obase + idx) = make_uint2(p0, p1);
    }
    if (tid < nL) scores[bt * nL + tid] = __expf(slog[tid] - mx) * rden;
}

// out = LN( wbuf + sum_l s_l * ff_b2[l] ) with ln_emb params
__global__ __launch_bounds__(256) void k_final(
    const float* __restrict__ wbuf, const float* __restrict__ scores,
    const float* __restrict__ ff_b2, const float* __restrict__ g,
    const float* __restrict__ bvec, float* __restrict__ out)
{
    const int bt = blockIdx.x;
    const int tid = threadIdx.x;
    __shared__ float ssc[nL];
    __shared__ float red[8];
    if (tid < nL) ssc[tid] = scores[bt * nL + tid];
    __syncthreads();
    const int e0 = tid * 4;
    float4 w = *reinterpret_cast<const float4*>(wbuf + (size_t)bt * nE + e0);
#pragma unroll
    for (int l = 0; l < nL; ++l) {
        float s = ssc[l];
        float4 b2 = *reinterpret_cast<const float4*>(ff_b2 + l * nE + e0);
        w.x += s * b2.x; w.y += s * b2.y; w.z += s * b2.z; w.w += s * b2.w;
    }
    float sum = w.x + w.y + w.z + w.w;
    float sq = w.x * w.x + w.y * w.y + w.z * w.z + w.w * w.w;
    int wid = tid >> 6, lane = tid & 63;
#pragma unroll
    for (int off = 32; off > 0; off >>= 1) {
        sum += __shfl_down(sum, off, 64); sq += __shfl_down(sq, off, 64);
    }
    if (lane == 0) { red[wid] = sum; red[4 + wid] = sq; }
    __syncthreads();
    sum = red[0] + red[1] + red[2] + red[3];
    sq  = red[4] + red[5] + red[6] + red[7];
    float mean = sum * (1.f / nE);
    float inv = rsqrtf(sq * (1.f / nE) - mean * mean + 1e-5f);
    float4 g4 = *reinterpret_cast<const float4*>(g + e0);
    float4 b4 = *reinterpret_cast<const float4*>(bvec + e0);
    float4 o;
    o.x = (w.x - mean) * inv * g4.x + b4.x;
    o.y = (w.y - mean) * inv * g4.y + b4.y;
    o.z = (w.z - mean) * inv * g4.z + b4.z;
    o.w = (w.w - mean) * inv * g4.w + b4.w;
    *reinterpret_cast<float4*>(out + (size_t)bt * nE + e0) = o;
}

extern "C" void kernel_launch(void* const* d_in, const int* in_sizes, int n_in,
                              void* d_out, int out_size, void* d_ws, size_t ws_size,
                              hipStream_t stream) {
    (void)in_sizes; (void)n_in; (void)out_size; (void)ws_size;
    const float* emb            = (const float*)d_in[0];
    const float* state_control  = (const float*)d_in[1];
    const float* input_influence= (const float*)d_in[2];
    const float* output_shaper  = (const float*)d_in[3];
    const float* glu_w          = (const float*)d_in[4];
    const float* glu_b          = (const float*)d_in[5];
    const float* e2s_w          = (const float*)d_in[6];
    const float* e2s_b          = (const float*)d_in[7];
    const float* ln_glu_g       = (const float*)d_in[8];
    const float* ln_glu_b       = (const float*)d_in[9];
    const float* ln_state_g     = (const float*)d_in[10];
    const float* ln_state_b     = (const float*)d_in[11];
    const float* ln_emb_g       = (const float*)d_in[12];
    const float* ln_emb_b       = (const float*)d_in[13];
    const float* ff_ln_g        = (const float*)d_in[14];
    const float* ff_ln_b        = (const float*)d_in[15];
    const float* ff_w1          = (const float*)d_in[16];
    const float* ff_b1          = (const float*)d_in[17];
    const float* ff_w2          = (const float*)d_in[18];
    const float* ff_b2          = (const float*)d_in[19];
    const float* attn_w         = (const float*)d_in[20];
    const float* attn_b         = (const float*)d_in[21];

    // workspace layout (~160 MB)
    char* ws = (char*)d_ws;
    float* tokens = (float*)ws;  ws += (size_t)nBT * nLD * 4;             // 67 MB
    float* vbuf   = (float*)ws;  ws += (size_t)nBT * nLD * 4;             // 67 MB
    uint4* wswz   = (uint4*)ws;  ws += (size_t)nL * 8 * 8 * 16 * 64 * 16; // 8 MB
    unsigned int* recsL = (unsigned int*)ws; ws += (size_t)2 * nL * nB * 128 * 16;  // 256 KB
    unsigned int* recsF = (unsigned int*)ws; ws += (size_t)2 * nL * nB * 128 * 16;  // 256 KB
    unsigned short* w1T = (unsigned short*)ws; ws += (size_t)nL * nD * nD * 2;     // 4 MB
    unsigned short* w2T = (unsigned short*)ws; ws += (size_t)nE * nLD * 2;         // 8 MB
    float* sc_sum = (float*)ws;  ws += nLD * 4;
    float* ii_sum = (float*)ws;  ws += nLD * 4;
    float* os_sum = (float*)ws;  ws += nLD * 4;
    float* w2a    = (float*)ws;  ws += nLD * 4;
    float* c2     = (float*)ws;  ws += 256;
    float* scores = (float*)ws;  ws += (size_t)nBT * nL * 4;
    // aliases:
    unsigned short* emb_bf = (unsigned short*)vbuf;                    // dead before scan writes v
    unsigned short* e2sT   = (unsigned short*)vbuf + (size_t)nBT * nE; // ditto (8 MB further)
    unsigned short* ybf    = (unsigned short*)tokens;                  // tokens dead after scan
    unsigned short* hbf    = (unsigned short*)tokens + (size_t)nBT * nLD;  // upper half
    float* wbuf = tokens;  // ybf dead after ff1 GEMM; disjoint from hbf

    // precompute
    k_init2<<<64, 256, 0, stream>>>(recsL, recsF);
    k_pack2<<<nL * 64, 256, 0, stream>>>(glu_w, wswz);
    k_wdot<<<1024, 256, 0, stream>>>(state_control, nullptr, sc_sum, nLD, nD);
    k_wdot<<<1024, 256, 0, stream>>>(input_influence, nullptr, ii_sum, nLD, nD);
    k_wdot<<<1024, 256, 0, stream>>>(output_shaper, nullptr, os_sum, nLD, nD);
    k_wdot<<<1024, 256, 0, stream>>>(ff_w2, attn_w, w2a, nLD, nE);
    k_wdot<<<2, 256, 0, stream>>>(ff_b2, attn_w, c2, nL, nE);
    k_cast<<<nBT * nE / 1024, 256, 0, stream>>>(emb, emb_bf, nBT * nE);
    k_transp<<<dim3(nLD / 32, nE / 32, 1), 256, 0, stream>>>(e2s_w, e2sT, nE, nLD, 0, 0);
    k_transp<<<dim3(nD / 32, nD / 32, nL), 256, 0, stream>>>(ff_w1, w1T, nD, nD,
                                                             (long long)nD * nD, (long long)nD * nD);
    k_transp<<<dim3(nE / 32, nLD / 32, 1), 256, 0, stream>>>(ff_w2, w2T, nLD, nE, 0, 0);

    // tokens = emb @ e2s_w + e2s_b   [4096 x 4096], K=1024  (bf16 MFMA)
    k_gemm_bf<0><<<dim3(32, 32, 1), 256, 0, stream>>>(
        emb_bf, nE, 0, e2sT, nE, 0, e2s_b, 0, tokens, nLD, 0, nBT, nLD, nE);

    // distributed recurrent scan -> raw v
    k_scan7<<<64, 512, 0, stream>>>(tokens, wswz, glu_b, sc_sum, ii_sum,
                                    ln_glu_g, ln_glu_b, ln_state_g, ln_state_b,
                                    vbuf, recsL, recsF);

    // y = LN_ff(LN_state(v) * os_sum) -> bf16 ybf
    k_y2<<<nBT * nL / 4, 256, 0, stream>>>(vbuf, os_sum,
                                           ln_state_g, ln_state_b,
                                           ff_ln_g, ff_ln_b, ybf);

    // h = GELU(y @ ff_w1 + ff_b1), per-layer batched (bf16 MFMA) -> vbuf fp32
    k_gemm_bf<1><<<dim3(4, 32, 8), 256, 0, stream>>>(
        ybf, nLD, nD, w1T, nD, (long long)nD * nD, ff_b1, nD,
        vbuf, nLD, nD, nBT, nD, nD);

    // scores; scaled h -> bf16 hbf
    k_scores<<<nBT, 256, 0, stream>>>(vbuf, w2a, c2, attn_b, hbf, scores);

    // weighted = (s*h) @ W2cat   [4096 x 1024], K=4096 (bf16 MFMA) -> wbuf
    k_gemm_bf<0><<<dim3(8, 32, 1), 256, 0, stream>>>(
        hbf, nLD, 0, w2T, nLD, 0, nullptr, 0, wbuf, nE, 0, nBT, nE, nLD);

    // out = LN(weighted + sum_l s_l*ff_b2[l])
    k_final<<<nBT, 256, 0, stream>>>(wbuf, scores, ff_b2, ln_emb_g, ln_emb_b, (float*)d_out);
}

// Round 12
// 2003.672 us; speedup vs baseline: 1.0897x; 1.0897x over previous
//
#include <hip/hip_runtime.h>
#include <hip/hip_bf16.h>
#include <math.h>

// Fixed problem dims
static constexpr int nB = 8, nT = 512, nE = 1024, nL = 8, nD = 512;
static constexpr int nBT = nB * nT;   // 4096 rows (b,t)
static constexpr int nLD = nL * nD;   // 4096

typedef __attribute__((ext_vector_type(8))) short short8v;  // 8 bf16 (4 VGPRs)
typedef __attribute__((ext_vector_type(4))) float f32x4;
typedef __attribute__((ext_vector_type(4))) unsigned int u32x4;  // asm-safe

__device__ __forceinline__ unsigned short f2bf(float f) {
    unsigned int u = __float_as_uint(f);
    return (unsigned short)((u + 0x7fffu + ((u >> 16) & 1u)) >> 16);  // RNE
}
__device__ __forceinline__ float bfu2f(unsigned short u) {
    return __uint_as_float(((unsigned int)u) << 16);
}
__device__ __forceinline__ float gelu_f(float x) {
    return 0.5f * x * (1.0f + erff(x * 0.70710678118654752f));  // exact GELU
}

// dst[r] = sum_i src[r,i] * (w ? w[i] : 1)
__global__ __launch_bounds__(256) void k_wdot(const float* __restrict__ src,
                                              const float* __restrict__ w,
                                              float* __restrict__ dst,
                                              int rows, int rowlen) {
    int row = blockIdx.x * 4 + (threadIdx.x >> 6);
    if (row >= rows) return;
    int lane = threadIdx.x & 63;
    const float* p = src + (size_t)row * rowlen;
    float s = 0.f;
    if (w) { for (int i = lane; i < rowlen; i += 64) s += p[i] * w[i]; }
    else   { for (int i = lane; i < rowlen; i += 64) s += p[i]; }
#pragma unroll
    for (int off = 32; off > 0; off >>= 1) s += __shfl_down(s, off, 64);
    if (lane == 0) dst[row] = s;
}

// zero all record tags (must run each launch: stale tags from the previous
// timed replay alias valid step numbers)
__global__ __launch_bounds__(256) void k_init2(unsigned int* recs) {
    int i = blockIdx.x * 256 + threadIdx.x;   // 16384 records
    if (i < 2 * nL * nB * 128)
        __hip_atomic_store(recs + i * 4 + 3, 0u,
                           __ATOMIC_RELAXED, __HIP_MEMORY_SCOPE_AGENT);
}

// flat fp32 -> bf16 cast
__global__ __launch_bounds__(256) void k_cast(const float* __restrict__ s,
                                              unsigned short* __restrict__ d, int n) {
    int idx = (blockIdx.x * 256 + threadIdx.x) * 4;
    if (idx >= n) return;
    float4 v = *reinterpret_cast<const float4*>(s + idx);
    ushort4 o;
    o.x = f2bf(v.x); o.y = f2bf(v.y); o.z = f2bf(v.z); o.w = f2bf(v.w);
    *reinterpret_cast<ushort4*>(d + idx) = o;
}

// tiled transpose-cast: dst[c][r] (bf16) = src[r][c] (fp32); batch via z
__global__ __launch_bounds__(256) void k_transp(const float* __restrict__ src,
                                                unsigned short* __restrict__ dst,
                                                int R, int Cc,
                                                long long sSrc, long long sDst) {
    src += (size_t)blockIdx.z * sSrc;
    dst += (size_t)blockIdx.z * sDst;
    __shared__ float t[32][33];
    const int tx = threadIdx.x & 31, ty = threadIdx.x >> 5;  // ty 0..7
    const int r0 = blockIdx.y * 32, c0 = blockIdx.x * 32;
#pragma unroll
    for (int r = 0; r < 4; ++r)
        t[ty + r * 8][tx] = src[(size_t)(r0 + ty + r * 8) * Cc + c0 + tx];
    __syncthreads();
#pragma unroll
    for (int r = 0; r < 4; ++r)
        dst[(size_t)(c0 + ty + r * 8) * R + r0 + tx] = f2bf(t[tx][ty + r * 8]);
}

// Pack glu_w into MFMA B-fragment layout with INTERLEAVED a/g columns.
__global__ __launch_bounds__(256) void k_pack2(const float* __restrict__ src,
                                               uint4* __restrict__ dst) {
    const int blk = blockIdx.x;            // l*64 + q*8 + w   (512 blocks)
    const int w = blk & 7, q = (blk >> 3) & 7, l = blk >> 6;
    const float* wl = src + (size_t)l * nD * 1024;
    for (int i = threadIdx.x; i < 16 * 64; i += 256) {
        const int kt = i >> 6, ln = i & 63;
        const int j = ln & 15, g = ln >> 4;
        const int u = j >> 1;
        const int col = (j & 1) ? (512 + q * 64 + w * 8 + u)
                                : (q * 64 + w * 8 + u);
        const int k0 = 32 * kt + 8 * g;
        unsigned pr[4];
#pragma unroll
        for (int p = 0; p < 4; ++p) {
            float a = wl[(size_t)(k0 + 2 * p) * 1024 + col];
            float c = wl[(size_t)(k0 + 2 * p + 1) * 1024 + col];
            pr[p] = (unsigned)f2bf(a) | ((unsigned)f2bf(c) << 16);
        }
        dst[((((size_t)l * 8 + q) * 8 + w) * 16 + kt) * 64 + ln] =
            make_uint4(pr[0], pr[1], pr[2], pr[3]);
    }
}

// ---------------------------------------------------------------------------
// bf16 MFMA GEMM (unchanged from R9)
// ---------------------------------------------------------------------------
template<int ACT>
__global__ __launch_bounds__(256) void k_gemm_bf(
    const unsigned short* __restrict__ A, int lda, long long sA,
    const unsigned short* __restrict__ Bt, int ldb, long long sB,
    const float* __restrict__ bias, long long sBias,
    float* __restrict__ C, int ldc, long long sC,
    int M, int N, int K)
{
    A  += (size_t)blockIdx.z * sA;
    Bt += (size_t)blockIdx.z * sB;
    C  += (size_t)blockIdx.z * sC;
    const float* biasp = bias ? bias + (size_t)blockIdx.z * sBias : nullptr;

    __shared__ __align__(16) unsigned short A_s[128][40];
    __shared__ __align__(16) unsigned short B_s[128][40];
    const int tid = threadIdx.x, lane = tid & 63;
    const int wv = tid >> 6;
    const int wm = (wv >> 1) * 64, wn = (wv & 1) * 64;
    const int bm = blockIdx.y * 128, bn = blockIdx.x * 128;
    const int srow = tid >> 2, sc8 = (tid & 3) * 8;

    f32x4 acc[4][4];
#pragma unroll
    for (int i = 0; i < 4; ++i)
#pragma unroll
        for (int j = 0; j < 4; ++j) acc[i][j] = f32x4{0.f, 0.f, 0.f, 0.f};

    const int fr = lane & 15, fg = (lane >> 4) * 8;

    for (int kt = 0; kt < K; kt += 32) {
        uint4 a0 = *reinterpret_cast<const uint4*>(A + (size_t)(bm + srow) * lda + kt + sc8);
        uint4 a1 = *reinterpret_cast<const uint4*>(A + (size_t)(bm + srow + 64) * lda + kt + sc8);
        uint4 b0 = *reinterpret_cast<const uint4*>(Bt + (size_t)(bn + srow) * ldb + kt + sc8);
        uint4 b1 = *reinterpret_cast<const uint4*>(Bt + (size_t)(bn + srow + 64) * ldb + kt + sc8);
        __syncthreads();
        *reinterpret_cast<uint4*>(&A_s[srow][sc8]) = a0;
        *reinterpret_cast<uint4*>(&A_s[srow + 64][sc8]) = a1;
        *reinterpret_cast<uint4*>(&B_s[srow][sc8]) = b0;
        *reinterpret_cast<uint4*>(&B_s[srow + 64][sc8]) = b1;
        __syncthreads();
        short8v af[4], bf[4];
#pragma unroll
        for (int mi = 0; mi < 4; ++mi)
            af[mi] = *reinterpret_cast<const short8v*>(&A_s[wm + mi * 16 + fr][fg]);
#pragma unroll
        for (int ni = 0; ni < 4; ++ni)
            bf[ni] = *reinterpret_cast<const short8v*>(&B_s[wn + ni * 16 + fr][fg]);
#pragma unroll
        for (int mi = 0; mi < 4; ++mi)
#pragma unroll
            for (int ni = 0; ni < 4; ++ni)
                acc[mi][ni] = __builtin_amdgcn_mfma_f32_16x16x32_bf16(
                    af[mi], bf[ni], acc[mi][ni], 0, 0, 0);
    }

#pragma unroll
    for (int mi = 0; mi < 4; ++mi)
#pragma unroll
        for (int ni = 0; ni < 4; ++ni) {
            const int col = bn + wn + ni * 16 + (lane & 15);
            const float bv = biasp ? biasp[col] : 0.f;
#pragma unroll
            for (int p = 0; p < 4; ++p) {
                const int row = bm + wm + mi * 16 + (lane >> 4) * 4 + p;
                float v = acc[mi][ni][p] + bv;
                if (ACT == 1) v = gelu_f(v);
                C[(size_t)row * ldc + col] = v;
            }
        }
}

// ---------------------------------------------------------------------------
// Scan (R9 protocol, single LLC mirror) + FUSED y-production:
// after publishing step t, each wave computes y[t-1] = LN_ff(LN_state(v)*os)
// from registers carried out of phase A -- the work hides in the publish->
// poll RT window. Epilogue poll (tag nT) produces y[nT-1]. vout eliminated.
// ---------------------------------------------------------------------------
__global__ __launch_bounds__(512, 1) void k_scan8(
    const float* __restrict__ tokens,      // [B,T,L,D]
    const uint4* __restrict__ wswz,        // packed B-fragments (interleaved)
    const float* __restrict__ glu_b,       // [L,2D]
    const float* __restrict__ sc_sum, const float* __restrict__ ii_sum,
    const float* __restrict__ os_sum,      // [L,D]
    const float* __restrict__ ln_glu_g, const float* __restrict__ ln_glu_b,
    const float* __restrict__ ln_state_g, const float* __restrict__ ln_state_b,
    const float* __restrict__ ff_ln_g, const float* __restrict__ ff_ln_b,  // [L,D]
    unsigned short* __restrict__ ybf,      // [B,T,L,D] bf16 y output
    unsigned int* __restrict__ recs)
{
    const int l = blockIdx.x & 7, q = blockIdx.x >> 3;
    const int tid = threadIdx.x, w = tid >> 6, lane = tid & 63;
    const int b = w;  // wave = batch

    __shared__ __align__(16) unsigned hn_pk[8][260];       // bf16 pairs, padded
    __shared__ __align__(16) unsigned zbuf[4];
    __shared__ __align__(16) unsigned short vrow[8][512];  // consumer v (bf16)
    __shared__ __align__(16) unsigned short vstage[8][64]; // producer stage
    __shared__ __align__(16) float vsq[8][8][2];           // [b][w]{S,Q}

    uint4 wr[16];
    {
        const uint4* wp = wswz + ((((size_t)l * 8 + q) * 8 + w) * 16) * 64 + lane;
#pragma unroll
        for (int kt = 0; kt < 16; ++kt) wr[kt] = wp[kt * 64];
    }
    const int d0 = lane * 8;
    float P_sc[8], P_ii[8], P_gg[8], P_gb[8], P_sg[8], P_sb[8];
    float P_os[8], P_fg[8], P_fb[8];
#pragma unroll
    for (int j = 0; j < 8; j += 4) {
        *reinterpret_cast<float4*>(&P_sc[j]) = *reinterpret_cast<const float4*>(sc_sum + l * nD + d0 + j);
        *reinterpret_cast<float4*>(&P_ii[j]) = *reinterpret_cast<const float4*>(ii_sum + l * nD + d0 + j);
        *reinterpret_cast<float4*>(&P_os[j]) = *reinterpret_cast<const float4*>(os_sum + l * nD + d0 + j);
        *reinterpret_cast<float4*>(&P_gg[j]) = *reinterpret_cast<const float4*>(ln_glu_g + d0 + j);
        *reinterpret_cast<float4*>(&P_gb[j]) = *reinterpret_cast<const float4*>(ln_glu_b + d0 + j);
        *reinterpret_cast<float4*>(&P_sg[j]) = *reinterpret_cast<const float4*>(ln_state_g + d0 + j);
        *reinterpret_cast<float4*>(&P_sb[j]) = *reinterpret_cast<const float4*>(ln_state_b + d0 + j);
        *reinterpret_cast<float4*>(&P_fg[j]) = *reinterpret_cast<const float4*>(ff_ln_g + l * nD + d0 + j);
        *reinterpret_cast<float4*>(&P_fb[j]) = *reinterpret_cast<const float4*>(ff_ln_b + l * nD + d0 + j);
    }
    const int cu = (lane & 15) >> 1;
    const int mycol = (lane & 1) ? (512 + q * 64 + w * 8 + cu)
                                 : (q * 64 + w * 8 + cu);
    const float bias_c = glu_b[l * 1024 + mycol];

    if (tid < 4) zbuf[tid] = 0u;

    const float* tokp = tokens + ((size_t)b * nT * nL + l) * nD + d0;

    const unsigned* afp; int astep;
    {
        int bb = lane & 15, g = lane >> 4;
        if (bb < 8) { afp = &hn_pk[bb][g * 4]; astep = 16; }
        else        { afp = &zbuf[0];          astep = 0;  }
    }
    __syncthreads();

    float4 tk0 = *reinterpret_cast<const float4*>(tokp);
    float4 tk1 = *reinterpret_cast<const float4*>(tokp + 4);

    float vvC[8], mvC = 0.f, ivC = 0.f;   // carried v[t-1] state for y-fold

    for (int t = 0; t < nT; ++t) {
        float tk[8] = {tk0.x, tk0.y, tk0.z, tk0.w, tk1.x, tk1.y, tk1.z, tk1.w};
        float h[8];
        if (t > 0) {
            const unsigned* rp = recs + ((((size_t)((t - 1) & 1) * nL + l) * nB + b) * 128) * 4;
            const unsigned* pa = rp + lane * 4;
            const unsigned* pb = rp + (lane + 64) * 4;
            u32x4 ra, rb;
            int ok;
            do {
                asm volatile(
                    "global_load_dwordx4 %0, %2, off sc0 sc1\n\t"
                    "global_load_dwordx4 %1, %3, off sc0 sc1\n\t"
                    "s_waitcnt vmcnt(0)"
                    : "=&v"(ra), "=&v"(rb)
                    : "v"(pa), "v"(pb)
                    : "memory");
                ok = (ra[3] == (unsigned)t) && (rb[3] == (unsigned)t);
            } while (!__all(ok));

            float S = 0.f, Q = 0.f;
            if (lane & 1) {
                S = __uint_as_float(ra[1]) + __uint_as_float(rb[1]);
                Q = __uint_as_float(ra[2]) + __uint_as_float(rb[2]);
            }
#pragma unroll
            for (int o = 32; o > 0; o >>= 1) { S += __shfl_xor(S, o, 64); Q += __shfl_xor(Q, o, 64); }
            mvC = S * (1.f / nD);
            ivC = rsqrtf(Q * (1.f / nD) - mvC * mvC + 1e-5f);

            {
                const int ia = lane, ib2 = lane + 64;
                const int qa = ia >> 4, wa = (ia >> 1) & 7, ja = ia & 1;
                const int qb2 = ib2 >> 4, wb2 = (ib2 >> 1) & 7;
                unsigned* da = reinterpret_cast<unsigned*>(&vrow[b][qa * 64 + wa * 8 + ja * 6]);
                unsigned* db = reinterpret_cast<unsigned*>(&vrow[b][qb2 * 64 + wb2 * 8 + ja * 6]);
                if (!ja) {
                    da[0] = ra[0]; da[1] = ra[1]; da[2] = ra[2];
                    db[0] = rb[0]; db[1] = rb[1]; db[2] = rb[2];
                } else {
                    da[0] = ra[0];
                    db[0] = rb[0];
                }
            }
            asm volatile("s_waitcnt lgkmcnt(0)" ::: "memory");
            __builtin_amdgcn_sched_barrier(0);
            uint4 pv = *reinterpret_cast<const uint4*>(&vrow[b][lane * 8]);
            vvC[0] = bfu2f((unsigned short)(pv.x & 0xffffu));
            vvC[1] = bfu2f((unsigned short)(pv.x >> 16));
            vvC[2] = bfu2f((unsigned short)(pv.y & 0xffffu));
            vvC[3] = bfu2f((unsigned short)(pv.y >> 16));
            vvC[4] = bfu2f((unsigned short)(pv.z & 0xffffu));
            vvC[5] = bfu2f((unsigned short)(pv.z >> 16));
            vvC[6] = bfu2f((unsigned short)(pv.w & 0xffffu));
            vvC[7] = bfu2f((unsigned short)(pv.w >> 16));
#pragma unroll
            for (int j = 0; j < 8; ++j) {
                float st = (vvC[j] - mvC) * ivC * P_sg[j] + P_sb[j];
                h[j] = st * P_sc[j] + tk[j] * P_ii[j];
            }
        } else {
#pragma unroll
            for (int j = 0; j < 8; ++j) h[j] = tk[j] * P_ii[j];
        }

        if (t + 1 < nT) {
            tk0 = *reinterpret_cast<const float4*>(tokp + (size_t)(t + 1) * nLD);
            tk1 = *reinterpret_cast<const float4*>(tokp + (size_t)(t + 1) * nLD + 4);
        }

        float S = 0.f, Q = 0.f;
#pragma unroll
        for (int j = 0; j < 8; ++j) { S += h[j]; Q += h[j] * h[j]; }
#pragma unroll
        for (int o = 32; o > 0; o >>= 1) { S += __shfl_xor(S, o, 64); Q += __shfl_xor(Q, o, 64); }
        const float mh = S * (1.f / nD);
        const float ih = rsqrtf(Q * (1.f / nD) - mh * mh + 1e-5f);
        unsigned pr[4];
#pragma unroll
        for (int p = 0; p < 4; ++p) {
            float a0 = (h[2 * p]     - mh) * ih * P_gg[2 * p]     + P_gb[2 * p];
            float a1 = (h[2 * p + 1] - mh) * ih * P_gg[2 * p + 1] + P_gb[2 * p + 1];
            pr[p] = (unsigned)f2bf(a0) | ((unsigned)f2bf(a1) << 16);
        }
        *reinterpret_cast<uint4*>(&hn_pk[b][lane * 4]) = make_uint4(pr[0], pr[1], pr[2], pr[3]);

        asm volatile("s_waitcnt lgkmcnt(0)" ::: "memory");
        __builtin_amdgcn_s_barrier();
        __builtin_amdgcn_sched_barrier(0);

        f32x4 acc0 = {0.f, 0.f, 0.f, 0.f}, acc1 = {0.f, 0.f, 0.f, 0.f};
#pragma unroll
        for (int kt = 0; kt < 8; ++kt) {
            short8v a0 = *reinterpret_cast<const short8v*>(afp + (2 * kt) * astep);
            short8v a1 = *reinterpret_cast<const short8v*>(afp + (2 * kt + 1) * astep);
            acc0 = __builtin_amdgcn_mfma_f32_16x16x32_bf16(
                a0, __builtin_bit_cast(short8v, wr[2 * kt]), acc0, 0, 0, 0);
            acc1 = __builtin_amdgcn_mfma_f32_16x16x32_bf16(
                a1, __builtin_bit_cast(short8v, wr[2 * kt + 1]), acc1, 0, 0, 0);
        }

        float x[4], y[4];
#pragma unroll
        for (int i = 0; i < 4; ++i) x[i] = acc0[i] + acc1[i] + bias_c;
#pragma unroll
        for (int i = 0; i < 4; ++i) y[i] = __shfl_xor(x[i], 1, 64);
        float sv[4], sq[4];
        const int r0 = (lane >> 4) * 4;
        const bool prod = (lane < 32) && !(lane & 1);
#pragma unroll
        for (int i = 0; i < 4; ++i) {
            float v = x[i] / (1.f + __expf(-y[i]));
            sv[i] = prod ? v : 0.f;
            sq[i] = prod ? v * v : 0.f;
            if (prod) vstage[r0 + i][w * 8 + cu] = f2bf(v);
        }
#pragma unroll
        for (int i = 0; i < 4; ++i) {
            sv[i] += __shfl_xor(sv[i], 2, 64); sq[i] += __shfl_xor(sq[i], 2, 64);
            sv[i] += __shfl_xor(sv[i], 4, 64); sq[i] += __shfl_xor(sq[i], 4, 64);
            sv[i] += __shfl_xor(sv[i], 8, 64); sq[i] += __shfl_xor(sq[i], 8, 64);
        }
        if (lane == 0 || lane == 16) {
#pragma unroll
            for (int i = 0; i < 4; ++i) {
                vsq[r0 + i][w][0] = sv[i];
                vsq[r0 + i][w][1] = sq[i];
            }
        }

        asm volatile("s_waitcnt lgkmcnt(0)" ::: "memory");
        __builtin_amdgcn_s_barrier();
        __builtin_amdgcn_sched_barrier(0);

        if (tid < 128) {
            const int bb = tid >> 4, wb = (tid >> 1) & 7, jb = tid & 1;
            const unsigned* vp = reinterpret_cast<const unsigned*>(&vstage[bb][wb * 8]);
            u32x4 rec;
            if (!jb) { rec[0] = vp[0]; rec[1] = vp[1]; rec[2] = vp[2]; }
            else {
                rec[0] = vp[3];
                rec[1] = __float_as_uint(vsq[bb][wb][0]);
                rec[2] = __float_as_uint(vsq[bb][wb][1]);
            }
            rec[3] = (unsigned)(t + 1);
            unsigned* dst = recs + (((((size_t)(t & 1) * nL + l) * nB + bb) * 128)
                                    + q * 16 + wb * 2 + jb) * 4;
            asm volatile("global_store_dwordx4 %0, %1, off sc0 sc1"
                         :: "v"(dst), "v"(rec) : "memory");
        }

        // ---- fused y[t-1] (hidden in the publish->poll RT window) ----
        if (t > 0) {
            float val[8], S2 = 0.f, Q2 = 0.f;
#pragma unroll
            for (int j = 0; j < 8; ++j) {
                float st = (vvC[j] - mvC) * ivC * P_sg[j] + P_sb[j];
                val[j] = st * P_os[j];
                S2 += val[j]; Q2 += val[j] * val[j];
            }
#pragma unroll
            for (int o = 32; o > 0; o >>= 1) { S2 += __shfl_xor(S2, o, 64); Q2 += __shfl_xor(Q2, o, 64); }
            const float m2 = S2 * (1.f / nD);
            const float i2 = rsqrtf(Q2 * (1.f / nD) - m2 * m2 + 1e-5f);
            unsigned pk[4];
#pragma unroll
            for (int p = 0; p < 4; ++p) {
                float o0 = (val[2 * p]     - m2) * i2 * P_fg[2 * p]     + P_fb[2 * p];
                float o1 = (val[2 * p + 1] - m2) * i2 * P_fg[2 * p + 1] + P_fb[2 * p + 1];
                pk[p] = (unsigned)f2bf(o0) | ((unsigned)f2bf(o1) << 16);
            }
            *reinterpret_cast<uint4*>(ybf + (((size_t)b * nT + (t - 1)) * nL + l) * nD + d0) =
                make_uint4(pk[0], pk[1], pk[2], pk[3]);
        }
    }

    // ---- epilogue: y[nT-1] from the final records (tag nT) ----
    {
        const unsigned tagf = (unsigned)nT;
        const unsigned* rp = recs + ((((size_t)((nT - 1) & 1) * nL + l) * nB + b) * 128) * 4;
        const unsigned* pa = rp + lane * 4;
        const unsigned* pb = rp + (lane + 64) * 4;
        u32x4 ra, rb;
        int ok;
        do {
            asm volatile(
                "global_load_dwordx4 %0, %2, off sc0 sc1\n\t"
                "global_load_dwordx4 %1, %3, off sc0 sc1\n\t"
                "s_waitcnt vmcnt(0)"
                : "=&v"(ra), "=&v"(rb)
                : "v"(pa), "v"(pb)
                : "memory");
            ok = (ra[3] == tagf) && (rb[3] == tagf);
        } while (!__all(ok));

        float S = 0.f, Q = 0.f;
        if (lane & 1) {
            S = __uint_as_float(ra[1]) + __uint_as_float(rb[1]);
            Q = __uint_as_float(ra[2]) + __uint_as_float(rb[2]);
        }
#pragma unroll
        for (int o = 32; o > 0; o >>= 1) { S += __shfl_xor(S, o, 64); Q += __shfl_xor(Q, o, 64); }
        const float mv = S * (1.f / nD);
        const float iv = rsqrtf(Q * (1.f / nD) - mv * mv + 1e-5f);
        {
            const int ia = lane, ib2 = lane + 64;
            const int qa = ia >> 4, wa = (ia >> 1) & 7, ja = ia & 1;
            const int qb2 = ib2 >> 4, wb2 = (ib2 >> 1) & 7;
            unsigned* da = reinterpret_cast<unsigned*>(&vrow[b][qa * 64 + wa * 8 + ja * 6]);
            unsigned* db = reinterpret_cast<unsigned*>(&vrow[b][qb2 * 64 + wb2 * 8 + ja * 6]);
            if (!ja) {
                da[0] = ra[0]; da[1] = ra[1]; da[2] = ra[2];
                db[0] = rb[0]; db[1] = rb[1]; db[2] = rb[2];
            } else {
                da[0] = ra[0];
                db[0] = rb[0];
            }
        }
        asm volatile("s_waitcnt lgkmcnt(0)" ::: "memory");
        __builtin_amdgcn_sched_barrier(0);
        uint4 pv = *reinterpret_cast<const uint4*>(&vrow[b][lane * 8]);
        float vv[8];
        vv[0] = bfu2f((unsigned short)(pv.x & 0xffffu));
        vv[1] = bfu2f((unsigned short)(pv.x >> 16));
        vv[2] = bfu2f((unsigned short)(pv.y & 0xffffu));
        vv[3] = bfu2f((unsigned short)(pv.y >> 16));
        vv[4] = bfu2f((unsigned short)(pv.z & 0xffffu));
        vv[5] = bfu2f((unsigned short)(pv.z >> 16));
        vv[6] = bfu2f((unsigned short)(pv.w & 0xffffu));
        vv[7] = bfu2f((unsigned short)(pv.w >> 16));
        float val[8], S2 = 0.f, Q2 = 0.f;
#pragma unroll
        for (int j = 0; j < 8; ++j) {
            float st = (vv[j] - mv) * iv * P_sg[j] + P_sb[j];
            val[j] = st * P_os[j];
            S2 += val[j]; Q2 += val[j] * val[j];
        }
#pragma unroll
        for (int o = 32; o > 0; o >>= 1) { S2 += __shfl_xor(S2, o, 64); Q2 += __shfl_xor(Q2, o, 64); }
        const float m2 = S2 * (1.f / nD);
        const float i2 = rsqrtf(Q2 * (1.f / nD) - m2 * m2 + 1e-5f);
        unsigned pk[4];
#pragma unroll
        for (int p = 0; p < 4; ++p) {
            float o0 = (val[2 * p]     - m2) * i2 * P_fg[2 * p]     + P_fb[2 * p];
            float o1 = (val[2 * p + 1] - m2) * i2 * P_fg[2 * p + 1] + P_fb[2 * p + 1];
            pk[p] = (unsigned)f2bf(o0) | ((unsigned)f2bf(o1) << 16);
        }
        *reinterpret_cast<uint4*>(ybf + (((size_t)b * nT + (nT - 1)) * nL + l) * nD + d0) =
            make_uint4(pk[0], pk[1], pk[2], pk[3]);
    }
}

// scores from h via w2a; softmax over L; write scaled h as bf16; store probs
__global__ __launch_bounds__(256) void k_scores(
    const float* __restrict__ h, const float* __restrict__ w2a,
    const float* __restrict__ c2, const float* __restrict__ attn_b,
    unsigned short* __restrict__ hbf, float* __restrict__ scores)
{
    const int bt = blockIdx.x;
    const int tid = threadIdx.x, wid = tid >> 6, lane = tid & 63;
    __shared__ float slog[nL];
    const float* hrow = h + (size_t)bt * nLD;
    for (int l = wid; l < nL; l += 4) {
        const float* hp = hrow + l * nD;
        const float* wp = w2a + l * nD;
        float s = 0.f;
        for (int i = lane; i < nD; i += 64) s += hp[i] * wp[i];
#pragma unroll
        for (int off = 32; off > 0; off >>= 1) s += __shfl_down(s, off, 64);
        if (lane == 0) slog[l] = s + c2[l] + attn_b[0];
    }
    __syncthreads();
    float mx = -1e30f;
#pragma unroll
    for (int l = 0; l < nL; ++l) mx = fmaxf(mx, slog[l]);
    float den = 0.f;
#pragma unroll
    for (int l = 0; l < nL; ++l) den += __expf(slog[l] - mx);
    float rden = 1.f / den;
    unsigned short* obase = hbf + (size_t)bt * nLD;
#pragma unroll
    for (int it = 0; it < 4; ++it) {
        int idx = tid * 4 + it * 1024;
        int l = idx >> 9;
        float s = __expf(slog[l] - mx) * rden;
        float4 v = *reinterpret_cast<const float4*>(hrow + idx);
        unsigned p0 = (unsigned)f2bf(v.x * s) | ((unsigned)f2bf(v.y * s) << 16);
        unsigned p1 = (unsigned)f2bf(v.z * s) | ((unsigned)f2bf(v.w * s) << 16);
        *reinterpret_cast<uint2*>(obase + idx) = make_uint2(p0, p1);
    }
    if (tid < nL) scores[bt * nL + tid] = __expf(slog[tid] - mx) * rden;
}

// out = LN( wbuf + sum_l s_l * ff_b2[l] ) with ln_emb params
__global__ __launch_bounds__(256) void k_final(
    const float* __restrict__ wbuf, const float* __restrict__ scores,
    const float* __restrict__ ff_b2, const float* __restrict__ g,
    const float* __restrict__ bvec, float* __restrict__ out)
{
    const int bt = blockIdx.x;
    const int tid = threadIdx.x;
    __shared__ float ssc[nL];
    __shared__ float red[8];
    if (tid < nL) ssc[tid] = scores[bt * nL + tid];
    __syncthreads();
    const int e0 = tid * 4;
    float4 w = *reinterpret_cast<const float4*>(wbuf + (size_t)bt * nE + e0);
#pragma unroll
    for (int l = 0; l < nL; ++l) {
        float s = ssc[l];
        float4 b2 = *reinterpret_cast<const float4*>(ff_b2 + l * nE + e0);
        w.x += s * b2.x; w.y += s * b2.y; w.z += s * b2.z; w.w += s * b2.w;
    }
    float sum = w.x + w.y + w.z + w.w;
    float sq = w.x * w.x + w.y * w.y + w.z * w.z + w.w * w.w;
    int wid = tid >> 6, lane = tid & 63;
#pragma unroll
    for (int off = 32; off > 0; off >>= 1) {
        sum += __shfl_down(sum, off, 64); sq += __shfl_down(sq, off, 64);
    }
    if (lane == 0) { red[wid] = sum; red[4 + wid] = sq; }
    __syncthreads();
    sum = red[0] + red[1] + red[2] + red[3];
    sq  = red[4] + red[5] + red[6] + red[7];
    float mean = sum * (1.f / nE);
    float inv = rsqrtf(sq * (1.f / nE) - mean * mean + 1e-5f);
    float4 g4 = *reinterpret_cast<const float4*>(g + e0);
    float4 b4 = *reinterpret_cast<const float4*>(bvec + e0);
    float4 o;
    o.x = (w.x - mean) * inv * g4.x + b4.x;
    o.y = (w.y - mean) * inv * g4.y + b4.y;
    o.z = (w.z - mean) * inv * g4.z + b4.z;
    o.w = (w.w - mean) * inv * g4.w + b4.w;
    *reinterpret_cast<float4*>(out + (size_t)bt * nE + e0) = o;
}

extern "C" void kernel_launch(void* const* d_in, const int* in_sizes, int n_in,
                              void* d_out, int out_size, void* d_ws, size_t ws_size,
                              hipStream_t stream) {
    (void)in_sizes; (void)n_in; (void)out_size; (void)ws_size;
    const float* emb            = (const float*)d_in[0];
    const float* state_control  = (const float*)d_in[1];
    const float* input_influence= (const float*)d_in[2];
    const float* output_shaper  = (const float*)d_in[3];
    const float* glu_w          = (const float*)d_in[4];
    const float* glu_b          = (const float*)d_in[5];
    const float* e2s_w          = (const float*)d_in[6];
    const float* e2s_b          = (const float*)d_in[7];
    const float* ln_glu_g       = (const float*)d_in[8];
    const float* ln_glu_b       = (const float*)d_in[9];
    const float* ln_state_g     = (const float*)d_in[10];
    const float* ln_state_b     = (const float*)d_in[11];
    const float* ln_emb_g       = (const float*)d_in[12];
    const float* ln_emb_b       = (const float*)d_in[13];
    const float* ff_ln_g        = (const float*)d_in[14];
    const float* ff_ln_b        = (const float*)d_in[15];
    const float* ff_w1          = (const float*)d_in[16];
    const float* ff_b1          = (const float*)d_in[17];
    const float* ff_w2          = (const float*)d_in[18];
    const float* ff_b2          = (const float*)d_in[19];
    const float* attn_w         = (const float*)d_in[20];
    const float* attn_b         = (const float*)d_in[21];

    // workspace layout (~160 MB)
    char* ws = (char*)d_ws;
    float* tokens = (float*)ws;  ws += (size_t)nBT * nLD * 4;             // 67 MB
    float* vbuf   = (float*)ws;  ws += (size_t)nBT * nLD * 4;             // 67 MB
    uint4* wswz   = (uint4*)ws;  ws += (size_t)nL * 8 * 8 * 16 * 64 * 16; // 8 MB
    unsigned int* recs = (unsigned int*)ws; ws += (size_t)2 * nL * nB * 128 * 16;  // 256 KB
    unsigned short* w1T = (unsigned short*)ws; ws += (size_t)nL * nD * nD * 2;     // 4 MB
    unsigned short* w2T = (unsigned short*)ws; ws += (size_t)nE * nLD * 2;         // 8 MB
    float* sc_sum = (float*)ws;  ws += nLD * 4;
    float* ii_sum = (float*)ws;  ws += nLD * 4;
    float* os_sum = (float*)ws;  ws += nLD * 4;
    float* w2a    = (float*)ws;  ws += nLD * 4;
    float* c2     = (float*)ws;  ws += 256;
    float* scores = (float*)ws;  ws += (size_t)nBT * nL * 4;
    // aliases (lifetimes):
    unsigned short* emb_bf = (unsigned short*)vbuf;                    // dead before scan writes ybf
    unsigned short* e2sT   = (unsigned short*)vbuf + (size_t)nBT * nE; // ditto
    unsigned short* ybf    = (unsigned short*)vbuf;                    // scan out; dead after ff1
    float* hfull           = tokens;                                   // ff1 out (tokens dead after scan)
    unsigned short* hbf    = (unsigned short*)vbuf;                    // scores out (ybf dead)
    float* wbuf            = tokens;                                   // final GEMM out (h dead)

    // precompute
    k_init2<<<64, 256, 0, stream>>>(recs);
    k_pack2<<<nL * 64, 256, 0, stream>>>(glu_w, wswz);
    k_wdot<<<1024, 256, 0, stream>>>(state_control, nullptr, sc_sum, nLD, nD);
    k_wdot<<<1024, 256, 0, stream>>>(input_influence, nullptr, ii_sum, nLD, nD);
    k_wdot<<<1024, 256, 0, stream>>>(output_shaper, nullptr, os_sum, nLD, nD);
    k_wdot<<<1024, 256, 0, stream>>>(ff_w2, attn_w, w2a, nLD, nE);
    k_wdot<<<2, 256, 0, stream>>>(ff_b2, attn_w, c2, nL, nE);
    k_cast<<<nBT * nE / 1024, 256, 0, stream>>>(emb, emb_bf, nBT * nE);
    k_transp<<<dim3(nLD / 32, nE / 32, 1), 256, 0, stream>>>(e2s_w, e2sT, nE, nLD, 0, 0);
    k_transp<<<dim3(nD / 32, nD / 32, nL), 256, 0, stream>>>(ff_w1, w1T, nD, nD,
                                                             (long long)nD * nD, (long long)nD * nD);
    k_transp<<<dim3(nE / 32, nLD / 32, 1), 256, 0, stream>>>(ff_w2, w2T, nLD, nE, 0, 0);

    // tokens = emb @ e2s_w + e2s_b   [4096 x 4096], K=1024  (bf16 MFMA)
    k_gemm_bf<0><<<dim3(32, 32, 1), 256, 0, stream>>>(
        emb_bf, nE, 0, e2sT, nE, 0, e2s_b, 0, tokens, nLD, 0, nBT, nLD, nE);

    // distributed recurrent scan -> ybf (y = LN_ff(LN_state(v)*os), fused)
    k_scan8<<<64, 512, 0, stream>>>(tokens, wswz, glu_b, sc_sum, ii_sum, os_sum,
                                    ln_glu_g, ln_glu_b, ln_state_g, ln_state_b,
                                    ff_ln_g, ff_ln_b, ybf, recs);

    // h = GELU(y @ ff_w1 + ff_b1), per-layer batched (bf16 MFMA) -> hfull
    k_gemm_bf<1><<<dim3(4, 32, 8), 256, 0, stream>>>(
        ybf, nLD, nD, w1T, nD, (long long)nD * nD, ff_b1, nD,
        hfull, nLD, nD, nBT, nD, nD);

    // scores; scaled h -> bf16 hbf
    k_scores<<<nBT, 256, 0, stream>>>(hfull, w2a, c2, attn_b, hbf, scores);

    // weighted = (s*h) @ W2cat   [4096 x 1024], K=4096 (bf16 MFMA) -> wbuf
    k_gemm_bf<0><<<dim3(8, 32, 1), 256, 0, stream>>>(
        hbf, nLD, 0, w2T, nLD, 0, nullptr, 0, wbuf, nE, 0, nBT, nE, nLD);

    // out = LN(weighted + sum_l s_l*ff_b2[l])
    k_final<<<nBT, 256, 0, stream>>>(wbuf, scores, ff_b2, ln_emb_g, ln_emb_b, (float*)d_out);
}

// Round 13
// 1958.091 us; speedup vs baseline: 1.1150x; 1.0233x over previous
//
#include <hip/hip_runtime.h>
#include <hip/hip_bf16.h>
#include <math.h>

// Fixed problem dims
static constexpr int nB = 8, nT = 512, nE = 1024, nL = 8, nD = 512;
static constexpr int nBT = nB * nT;   // 4096 rows (b,t)
static constexpr int nLD = nL * nD;   // 4096

typedef __attribute__((ext_vector_type(8))) short short8v;  // 8 bf16 (4 VGPRs)
typedef __attribute__((ext_vector_type(4))) float f32x4;
typedef __attribute__((ext_vector_type(4))) unsigned int u32x4;  // asm-safe

__device__ __forceinline__ unsigned short f2bf(float f) {
    unsigned int u = __float_as_uint(f);
    return (unsigned short)((u + 0x7fffu + ((u >> 16) & 1u)) >> 16);  // RNE
}
__device__ __forceinline__ float bfu2f(unsigned short u) {
    return __uint_as_float(((unsigned int)u) << 16);
}
__device__ __forceinline__ float gelu_f(float x) {
    return 0.5f * x * (1.0f + erff(x * 0.70710678118654752f));  // exact GELU
}

// dst[r] = sum_i src[r,i] * (w ? w[i] : 1)
__global__ __launch_bounds__(256) void k_wdot(const float* __restrict__ src,
                                              const float* __restrict__ w,
                                              float* __restrict__ dst,
                                              int rows, int rowlen) {
    int row = blockIdx.x * 4 + (threadIdx.x >> 6);
    if (row >= rows) return;
    int lane = threadIdx.x & 63;
    const float* p = src + (size_t)row * rowlen;
    float s = 0.f;
    if (w) { for (int i = lane; i < rowlen; i += 64) s += p[i] * w[i]; }
    else   { for (int i = lane; i < rowlen; i += 64) s += p[i]; }
#pragma unroll
    for (int off = 32; off > 0; off >>= 1) s += __shfl_down(s, off, 64);
    if (lane == 0) dst[row] = s;
}

// zero all record tags (must run each launch: stale tags from the previous
// timed replay alias valid step numbers)
__global__ __launch_bounds__(256) void k_init2(unsigned int* recs) {
    int i = blockIdx.x * 256 + threadIdx.x;   // 16384 records
    if (i < 2 * nL * nB * 128)
        __hip_atomic_store(recs + i * 4 + 3, 0u,
                           __ATOMIC_RELAXED, __HIP_MEMORY_SCOPE_AGENT);
}

// flat fp32 -> bf16 cast
__global__ __launch_bounds__(256) void k_cast(const float* __restrict__ s,
                                              unsigned short* __restrict__ d, int n) {
    int idx = (blockIdx.x * 256 + threadIdx.x) * 4;
    if (idx >= n) return;
    float4 v = *reinterpret_cast<const float4*>(s + idx);
    ushort4 o;
    o.x = f2bf(v.x); o.y = f2bf(v.y); o.z = f2bf(v.z); o.w = f2bf(v.w);
    *reinterpret_cast<ushort4*>(d + idx) = o;
}

// tiled transpose-cast: dst[c][r] (bf16) = src[r][c] (fp32); batch via z
__global__ __launch_bounds__(256) void k_transp(const float* __restrict__ src,
                                                unsigned short* __restrict__ dst,
                                                int R, int Cc,
                                                long long sSrc, long long sDst) {
    src += (size_t)blockIdx.z * sSrc;
    dst += (size_t)blockIdx.z * sDst;
    __shared__ float t[32][33];
    const int tx = threadIdx.x & 31, ty = threadIdx.x >> 5;  // ty 0..7
    const int r0 = blockIdx.y * 32, c0 = blockIdx.x * 32;
#pragma unroll
    for (int r = 0; r < 4; ++r)
        t[ty + r * 8][tx] = src[(size_t)(r0 + ty + r * 8) * Cc + c0 + tx];
    __syncthreads();
#pragma unroll
    for (int r = 0; r < 4; ++r)
        dst[(size_t)(c0 + ty + r * 8) * R + r0 + tx] = f2bf(t[tx][ty + r * 8]);
}

// Pack glu_w into MFMA B-fragment layout with INTERLEAVED a/g columns.
__global__ __launch_bounds__(256) void k_pack2(const float* __restrict__ src,
                                               uint4* __restrict__ dst) {
    const int blk = blockIdx.x;            // l*64 + q*8 + w   (512 blocks)
    const int w = blk & 7, q = (blk >> 3) & 7, l = blk >> 6;
    const float* wl = src + (size_t)l * nD * 1024;
    for (int i = threadIdx.x; i < 16 * 64; i += 256) {
        const int kt = i >> 6, ln = i & 63;
        const int j = ln & 15, g = ln >> 4;
        const int u = j >> 1;
        const int col = (j & 1) ? (512 + q * 64 + w * 8 + u)
                                : (q * 64 + w * 8 + u);
        const int k0 = 32 * kt + 8 * g;
        unsigned pr[4];
#pragma unroll
        for (int p = 0; p < 4; ++p) {
            float a = wl[(size_t)(k0 + 2 * p) * 1024 + col];
            float c = wl[(size_t)(k0 + 2 * p + 1) * 1024 + col];
            pr[p] = (unsigned)f2bf(a) | ((unsigned)f2bf(c) << 16);
        }
        dst[((((size_t)l * 8 + q) * 8 + w) * 16 + kt) * 64 + ln] =
            make_uint4(pr[0], pr[1], pr[2], pr[3]);
    }
}

// ---------------------------------------------------------------------------
// bf16 MFMA GEMM, now SOFTWARE-PIPELINED: iteration kt issues kt+1's global
// loads right after the LDS-write barrier, so HBM/L2 latency hides under the
// 16-MFMA compute block (previously loads waited for compute to finish).
// ---------------------------------------------------------------------------
template<int ACT>
__global__ __launch_bounds__(256) void k_gemm_bf(
    const unsigned short* __restrict__ A, int lda, long long sA,
    const unsigned short* __restrict__ Bt, int ldb, long long sB,
    const float* __restrict__ bias, long long sBias,
    float* __restrict__ C, int ldc, long long sC,
    int M, int N, int K)
{
    A  += (size_t)blockIdx.z * sA;
    Bt += (size_t)blockIdx.z * sB;
    C  += (size_t)blockIdx.z * sC;
    const float* biasp = bias ? bias + (size_t)blockIdx.z * sBias : nullptr;

    __shared__ __align__(16) unsigned short A_s[128][40];
    __shared__ __align__(16) unsigned short B_s[128][40];
    const int tid = threadIdx.x, lane = tid & 63;
    const int wv = tid >> 6;
    const int wm = (wv >> 1) * 64, wn = (wv & 1) * 64;
    const int bm = blockIdx.y * 128, bn = blockIdx.x * 128;
    const int srow = tid >> 2, sc8 = (tid & 3) * 8;

    f32x4 acc[4][4];
#pragma unroll
    for (int i = 0; i < 4; ++i)
#pragma unroll
        for (int j = 0; j < 4; ++j) acc[i][j] = f32x4{0.f, 0.f, 0.f, 0.f};

    const int fr = lane & 15, fg = (lane >> 4) * 8;

    const unsigned short* pA0 = A + (size_t)(bm + srow) * lda + sc8;
    const unsigned short* pA1 = A + (size_t)(bm + srow + 64) * lda + sc8;
    const unsigned short* pB0 = Bt + (size_t)(bn + srow) * ldb + sc8;
    const unsigned short* pB1 = Bt + (size_t)(bn + srow + 64) * ldb + sc8;

    uint4 a0 = *reinterpret_cast<const uint4*>(pA0);
    uint4 a1 = *reinterpret_cast<const uint4*>(pA1);
    uint4 b0 = *reinterpret_cast<const uint4*>(pB0);
    uint4 b1 = *reinterpret_cast<const uint4*>(pB1);

    for (int kt = 0; kt < K; kt += 32) {
        __syncthreads();  // prior compute done before overwriting LDS
        *reinterpret_cast<uint4*>(&A_s[srow][sc8]) = a0;
        *reinterpret_cast<uint4*>(&A_s[srow + 64][sc8]) = a1;
        *reinterpret_cast<uint4*>(&B_s[srow][sc8]) = b0;
        *reinterpret_cast<uint4*>(&B_s[srow + 64][sc8]) = b1;
        __syncthreads();

        const bool more = (kt + 32 < K);
        if (more) {  // issue next tile's loads; they fly during MFMA below
            a0 = *reinterpret_cast<const uint4*>(pA0 + kt + 32);
            a1 = *reinterpret_cast<const uint4*>(pA1 + kt + 32);
            b0 = *reinterpret_cast<const uint4*>(pB0 + kt + 32);
            b1 = *reinterpret_cast<const uint4*>(pB1 + kt + 32);
        }

        short8v af[4], bf[4];
#pragma unroll
        for (int mi = 0; mi < 4; ++mi)
            af[mi] = *reinterpret_cast<const short8v*>(&A_s[wm + mi * 16 + fr][fg]);
#pragma unroll
        for (int ni = 0; ni < 4; ++ni)
            bf[ni] = *reinterpret_cast<const short8v*>(&B_s[wn + ni * 16 + fr][fg]);
#pragma unroll
        for (int mi = 0; mi < 4; ++mi)
#pragma unroll
            for (int ni = 0; ni < 4; ++ni)
                acc[mi][ni] = __builtin_amdgcn_mfma_f32_16x16x32_bf16(
                    af[mi], bf[ni], acc[mi][ni], 0, 0, 0);
    }

#pragma unroll
    for (int mi = 0; mi < 4; ++mi)
#pragma unroll
        for (int ni = 0; ni < 4; ++ni) {
            const int col = bn + wn + ni * 16 + (lane & 15);
            const float bv = biasp ? biasp[col] : 0.f;
#pragma unroll
            for (int p = 0; p < 4; ++p) {
                const int row = bm + wm + mi * 16 + (lane >> 4) * 4 + p;
                float v = acc[mi][ni][p] + bv;
                if (ACT == 1) v = gelu_f(v);
                C[(size_t)row * ldc + col] = v;
            }
        }
}

// ---------------------------------------------------------------------------
// Scan (R12 structure) with st[] cached: LN_state(v) computed ONCE per step
// and reused by the y-fold (saves ~32 VALU ops/step and 10 carried VGPRs).
// ---------------------------------------------------------------------------
__global__ __launch_bounds__(512, 1) void k_scan8(
    const float* __restrict__ tokens,      // [B,T,L,D]
    const uint4* __restrict__ wswz,        // packed B-fragments (interleaved)
    const float* __restrict__ glu_b,       // [L,2D]
    const float* __restrict__ sc_sum, const float* __restrict__ ii_sum,
    const float* __restrict__ os_sum,      // [L,D]
    const float* __restrict__ ln_glu_g, const float* __restrict__ ln_glu_b,
    const float* __restrict__ ln_state_g, const float* __restrict__ ln_state_b,
    const float* __restrict__ ff_ln_g, const float* __restrict__ ff_ln_b,  // [L,D]
    unsigned short* __restrict__ ybf,      // [B,T,L,D] bf16 y output
    unsigned int* __restrict__ recs)
{
    const int l = blockIdx.x & 7, q = blockIdx.x >> 3;
    const int tid = threadIdx.x, w = tid >> 6, lane = tid & 63;
    const int b = w;  // wave = batch

    __shared__ __align__(16) unsigned hn_pk[8][260];       // bf16 pairs, padded
    __shared__ __align__(16) unsigned zbuf[4];
    __shared__ __align__(16) unsigned short vrow[8][512];  // consumer v (bf16)
    __shared__ __align__(16) unsigned short vstage[8][64]; // producer stage
    __shared__ __align__(16) float vsq[8][8][2];           // [b][w]{S,Q}

    uint4 wr[16];
    {
        const uint4* wp = wswz + ((((size_t)l * 8 + q) * 8 + w) * 16) * 64 + lane;
#pragma unroll
        for (int kt = 0; kt < 16; ++kt) wr[kt] = wp[kt * 64];
    }
    const int d0 = lane * 8;
    float P_sc[8], P_ii[8], P_gg[8], P_gb[8], P_sg[8], P_sb[8];
    float P_os[8], P_fg[8], P_fb[8];
#pragma unroll
    for (int j = 0; j < 8; j += 4) {
        *reinterpret_cast<float4*>(&P_sc[j]) = *reinterpret_cast<const float4*>(sc_sum + l * nD + d0 + j);
        *reinterpret_cast<float4*>(&P_ii[j]) = *reinterpret_cast<const float4*>(ii_sum + l * nD + d0 + j);
        *reinterpret_cast<float4*>(&P_os[j]) = *reinterpret_cast<const float4*>(os_sum + l * nD + d0 + j);
        *reinterpret_cast<float4*>(&P_gg[j]) = *reinterpret_cast<const float4*>(ln_glu_g + d0 + j);
        *reinterpret_cast<float4*>(&P_gb[j]) = *reinterpret_cast<const float4*>(ln_glu_b + d0 + j);
        *reinterpret_cast<float4*>(&P_sg[j]) = *reinterpret_cast<const float4*>(ln_state_g + d0 + j);
        *reinterpret_cast<float4*>(&P_sb[j]) = *reinterpret_cast<const float4*>(ln_state_b + d0 + j);
        *reinterpret_cast<float4*>(&P_fg[j]) = *reinterpret_cast<const float4*>(ff_ln_g + l * nD + d0 + j);
        *reinterpret_cast<float4*>(&P_fb[j]) = *reinterpret_cast<const float4*>(ff_ln_b + l * nD + d0 + j);
    }
    const int cu = (lane & 15) >> 1;
    const int mycol = (lane & 1) ? (512 + q * 64 + w * 8 + cu)
                                 : (q * 64 + w * 8 + cu);
    const float bias_c = glu_b[l * 1024 + mycol];

    if (tid < 4) zbuf[tid] = 0u;

    const float* tokp = tokens + ((size_t)b * nT * nL + l) * nD + d0;

    const unsigned* afp; int astep;
    {
        int bb = lane & 15, g = lane >> 4;
        if (bb < 8) { afp = &hn_pk[bb][g * 4]; astep = 16; }
        else        { afp = &zbuf[0];          astep = 0;  }
    }
    __syncthreads();

    float4 tk0 = *reinterpret_cast<const float4*>(tokp);
    float4 tk1 = *reinterpret_cast<const float4*>(tokp + 4);

    float stC[8];   // cached LN_state(v[t-1]) for the y-fold

    for (int t = 0; t < nT; ++t) {
        float tk[8] = {tk0.x, tk0.y, tk0.z, tk0.w, tk1.x, tk1.y, tk1.z, tk1.w};
        float h[8];
        if (t > 0) {
            const unsigned* rp = recs + ((((size_t)((t - 1) & 1) * nL + l) * nB + b) * 128) * 4;
            const unsigned* pa = rp + lane * 4;
            const unsigned* pb = rp + (lane + 64) * 4;
            u32x4 ra, rb;
            int ok;
            do {
                asm volatile(
                    "global_load_dwordx4 %0, %2, off sc0 sc1\n\t"
                    "global_load_dwordx4 %1, %3, off sc0 sc1\n\t"
                    "s_waitcnt vmcnt(0)"
                    : "=&v"(ra), "=&v"(rb)
                    : "v"(pa), "v"(pb)
                    : "memory");
                ok = (ra[3] == (unsigned)t) && (rb[3] == (unsigned)t);
            } while (!__all(ok));

            float S = 0.f, Q = 0.f;
            if (lane & 1) {
                S = __uint_as_float(ra[1]) + __uint_as_float(rb[1]);
                Q = __uint_as_float(ra[2]) + __uint_as_float(rb[2]);
            }
#pragma unroll
            for (int o = 32; o > 0; o >>= 1) { S += __shfl_xor(S, o, 64); Q += __shfl_xor(Q, o, 64); }
            const float mv = S * (1.f / nD);
            const float iv = rsqrtf(Q * (1.f / nD) - mv * mv + 1e-5f);

            {
                const int ia = lane, ib2 = lane + 64;
                const int qa = ia >> 4, wa = (ia >> 1) & 7, ja = ia & 1;
                const int qb2 = ib2 >> 4, wb2 = (ib2 >> 1) & 7;
                unsigned* da = reinterpret_cast<unsigned*>(&vrow[b][qa * 64 + wa * 8 + ja * 6]);
                unsigned* db = reinterpret_cast<unsigned*>(&vrow[b][qb2 * 64 + wb2 * 8 + ja * 6]);
                if (!ja) {
                    da[0] = ra[0]; da[1] = ra[1]; da[2] = ra[2];
                    db[0] = rb[0]; db[1] = rb[1]; db[2] = rb[2];
                } else {
                    da[0] = ra[0];
                    db[0] = rb[0];
                }
            }
            asm volatile("s_waitcnt lgkmcnt(0)" ::: "memory");
            __builtin_amdgcn_sched_barrier(0);
            uint4 pv = *reinterpret_cast<const uint4*>(&vrow[b][lane * 8]);
            float vv[8];
            vv[0] = bfu2f((unsigned short)(pv.x & 0xffffu));
            vv[1] = bfu2f((unsigned short)(pv.x >> 16));
            vv[2] = bfu2f((unsigned short)(pv.y & 0xffffu));
            vv[3] = bfu2f((unsigned short)(pv.y >> 16));
            vv[4] = bfu2f((unsigned short)(pv.z & 0xffffu));
            vv[5] = bfu2f((unsigned short)(pv.z >> 16));
            vv[6] = bfu2f((unsigned short)(pv.w & 0xffffu));
            vv[7] = bfu2f((unsigned short)(pv.w >> 16));
#pragma unroll
            for (int j = 0; j < 8; ++j) {
                stC[j] = (vv[j] - mv) * iv * P_sg[j] + P_sb[j];
                h[j] = stC[j] * P_sc[j] + tk[j] * P_ii[j];
            }
        } else {
#pragma unroll
            for (int j = 0; j < 8; ++j) h[j] = tk[j] * P_ii[j];
        }

        if (t + 1 < nT) {
            tk0 = *reinterpret_cast<const float4*>(tokp + (size_t)(t + 1) * nLD);
            tk1 = *reinterpret_cast<const float4*>(tokp + (size_t)(t + 1) * nLD + 4);
        }

        float S = 0.f, Q = 0.f;
#pragma unroll
        for (int j = 0; j < 8; ++j) { S += h[j]; Q += h[j] * h[j]; }
#pragma unroll
        for (int o = 32; o > 0; o >>= 1) { S += __shfl_xor(S, o, 64); Q += __shfl_xor(Q, o, 64); }
        const float mh = S * (1.f / nD);
        const float ih = rsqrtf(Q * (1.f / nD) - mh * mh + 1e-5f);
        unsigned pr[4];
#pragma unroll
        for (int p = 0; p < 4; ++p) {
            float a0 = (h[2 * p]     - mh) * ih * P_gg[2 * p]     + P_gb[2 * p];
            float a1 = (h[2 * p + 1] - mh) * ih * P_gg[2 * p + 1] + P_gb[2 * p + 1];
            pr[p] = (unsigned)f2bf(a0) | ((unsigned)f2bf(a1) << 16);
        }
        *reinterpret_cast<uint4*>(&hn_pk[b][lane * 4]) = make_uint4(pr[0], pr[1], pr[2], pr[3]);

        asm volatile("s_waitcnt lgkmcnt(0)" ::: "memory");
        __builtin_amdgcn_s_barrier();
        __builtin_amdgcn_sched_barrier(0);

        f32x4 acc0 = {0.f, 0.f, 0.f, 0.f}, acc1 = {0.f, 0.f, 0.f, 0.f};
#pragma unroll
        for (int kt = 0; kt < 8; ++kt) {
            short8v a0 = *reinterpret_cast<const short8v*>(afp + (2 * kt) * astep);
            short8v a1 = *reinterpret_cast<const short8v*>(afp + (2 * kt + 1) * astep);
            acc0 = __builtin_amdgcn_mfma_f32_16x16x32_bf16(
                a0, __builtin_bit_cast(short8v, wr[2 * kt]), acc0, 0, 0, 0);
            acc1 = __builtin_amdgcn_mfma_f32_16x16x32_bf16(
                a1, __builtin_bit_cast(short8v, wr[2 * kt + 1]), acc1, 0, 0, 0);
        }

        float x[4], y[4];
#pragma unroll
        for (int i = 0; i < 4; ++i) x[i] = acc0[i] + acc1[i] + bias_c;
#pragma unroll
        for (int i = 0; i < 4; ++i) y[i] = __shfl_xor(x[i], 1, 64);
        float sv[4], sq[4];
        const int r0 = (lane >> 4) * 4;
        const bool prod = (lane < 32) && !(lane & 1);
#pragma unroll
        for (int i = 0; i < 4; ++i) {
            float v = x[i] / (1.f + __expf(-y[i]));
            sv[i] = prod ? v : 0.f;
            sq[i] = prod ? v * v : 0.f;
            if (prod) vstage[r0 + i][w * 8 + cu] = f2bf(v);
        }
#pragma unroll
        for (int i = 0; i < 4; ++i) {
            sv[i] += __shfl_xor(sv[i], 2, 64); sq[i] += __shfl_xor(sq[i], 2, 64);
            sv[i] += __shfl_xor(sv[i], 4, 64); sq[i] += __shfl_xor(sq[i], 4, 64);
            sv[i] += __shfl_xor(sv[i], 8, 64); sq[i] += __shfl_xor(sq[i], 8, 64);
        }
        if (lane == 0 || lane == 16) {
#pragma unroll
            for (int i = 0; i < 4; ++i) {
                vsq[r0 + i][w][0] = sv[i];
                vsq[r0 + i][w][1] = sq[i];
            }
        }

        asm volatile("s_waitcnt lgkmcnt(0)" ::: "memory");
        __builtin_amdgcn_s_barrier();
        __builtin_amdgcn_sched_barrier(0);

        if (tid < 128) {
            const int bb = tid >> 4, wb = (tid >> 1) & 7, jb = tid & 1;
            const unsigned* vp = reinterpret_cast<const unsigned*>(&vstage[bb][wb * 8]);
            u32x4 rec;
            if (!jb) { rec[0] = vp[0]; rec[1] = vp[1]; rec[2] = vp[2]; }
            else {
                rec[0] = vp[3];
                rec[1] = __float_as_uint(vsq[bb][wb][0]);
                rec[2] = __float_as_uint(vsq[bb][wb][1]);
            }
            rec[3] = (unsigned)(t + 1);
            unsigned* dst = recs + (((((size_t)(t & 1) * nL + l) * nB + bb) * 128)
                                    + q * 16 + wb * 2 + jb) * 4;
            asm volatile("global_store_dwordx4 %0, %1, off sc0 sc1"
                         :: "v"(dst), "v"(rec) : "memory");
        }

        // ---- fused y[t-1] from cached stC (hidden in publish->poll window) ----
        if (t > 0) {
            float val[8], S2 = 0.f, Q2 = 0.f;
#pragma unroll
            for (int j = 0; j < 8; ++j) {
                val[j] = stC[j] * P_os[j];
                S2 += val[j]; Q2 += val[j] * val[j];
            }
#pragma unroll
            for (int o = 32; o > 0; o >>= 1) { S2 += __shfl_xor(S2, o, 64); Q2 += __shfl_xor(Q2, o, 64); }
            const float m2 = S2 * (1.f / nD);
            const float i2 = rsqrtf(Q2 * (1.f / nD) - m2 * m2 + 1e-5f);
            unsigned pk[4];
#pragma unroll
            for (int p = 0; p < 4; ++p) {
                float o0 = (val[2 * p]     - m2) * i2 * P_fg[2 * p]     + P_fb[2 * p];
                float o1 = (val[2 * p + 1] - m2) * i2 * P_fg[2 * p + 1] + P_fb[2 * p + 1];
                pk[p] = (unsigned)f2bf(o0) | ((unsigned)f2bf(o1) << 16);
            }
            *reinterpret_cast<uint4*>(ybf + (((size_t)b * nT + (t - 1)) * nL + l) * nD + d0) =
                make_uint4(pk[0], pk[1], pk[2], pk[3]);
        }
    }

    // ---- epilogue: y[nT-1] from the final records (tag nT) ----
    {
        const unsigned tagf = (unsigned)nT;
        const unsigned* rp = recs + ((((size_t)((nT - 1) & 1) * nL + l) * nB + b) * 128) * 4;
        const unsigned* pa = rp + lane * 4;
        const unsigned* pb = rp + (lane + 64) * 4;
        u32x4 ra, rb;
        int ok;
        do {
            asm volatile(
                "global_load_dwordx4 %0, %2, off sc0 sc1\n\t"
                "global_load_dwordx4 %1, %3, off sc0 sc1\n\t"
                "s_waitcnt vmcnt(0)"
                : "=&v"(ra), "=&v"(rb)
                : "v"(pa), "v"(pb)
                : "memory");
            ok = (ra[3] == tagf) && (rb[3] == tagf);
        } while (!__all(ok));

        float S = 0.f, Q = 0.f;
        if (lane & 1) {
            S = __uint_as_float(ra[1]) + __uint_as_float(rb[1]);
            Q = __uint_as_float(ra[2]) + __uint_as_float(rb[2]);
        }
#pragma unroll
        for (int o = 32; o > 0; o >>= 1) { S += __shfl_xor(S, o, 64); Q += __shfl_xor(Q, o, 64); }
        const float mv = S * (1.f / nD);
        const float iv = rsqrtf(Q * (1.f / nD) - mv * mv + 1e-5f);
        {
            const int ia = lane, ib2 = lane + 64;
            const int qa = ia >> 4, wa = (ia >> 1) & 7, ja = ia & 1;
            const int qb2 = ib2 >> 4, wb2 = (ib2 >> 1) & 7;
            unsigned* da = reinterpret_cast<unsigned*>(&vrow[b][qa * 64 + wa * 8 + ja * 6]);
            unsigned* db = reinterpret_cast<unsigned*>(&vrow[b][qb2 * 64 + wb2 * 8 + ja * 6]);
            if (!ja) {
                da[0] = ra[0]; da[1] = ra[1]; da[2] = ra[2];
                db[0] = rb[0]; db[1] = rb[1]; db[2] = rb[2];
            } else {
                da[0] = ra[0];
                db[0] = rb[0];
            }
        }
        asm volatile("s_waitcnt lgkmcnt(0)" ::: "memory");
        __builtin_amdgcn_sched_barrier(0);
        uint4 pv = *reinterpret_cast<const uint4*>(&vrow[b][lane * 8]);
        float vv[8];
        vv[0] = bfu2f((unsigned short)(pv.x & 0xffffu));
        vv[1] = bfu2f((unsigned short)(pv.x >> 16));
        vv[2] = bfu2f((unsigned short)(pv.y & 0xffffu));
        vv[3] = bfu2f((unsigned short)(pv.y >> 16));
        vv[4] = bfu2f((unsigned short)(pv.z & 0xffffu));
        vv[5] = bfu2f((unsigned short)(pv.z >> 16));
        vv[6] = bfu2f((unsigned short)(pv.w & 0xffffu));
        vv[7] = bfu2f((unsigned short)(pv.w >> 16));
        float val[8], S2 = 0.f, Q2 = 0.f;
#pragma unroll
        for (int j = 0; j < 8; ++j) {
            float st = (vv[j] - mv) * iv * P_sg[j] + P_sb[j];
            val[j] = st * P_os[j];
            S2 += val[j]; Q2 += val[j] * val[j];
        }
#pragma unroll
        for (int o = 32; o > 0; o >>= 1) { S2 += __shfl_xor(S2, o, 64); Q2 += __shfl_xor(Q2, o, 64); }
        const float m2 = S2 * (1.f / nD);
        const float i2 = rsqrtf(Q2 * (1.f / nD) - m2 * m2 + 1e-5f);
        unsigned pk[4];
#pragma unroll
        for (int p = 0; p < 4; ++p) {
            float o0 = (val[2 * p]     - m2) * i2 * P_fg[2 * p]     + P_fb[2 * p];
            float o1 = (val[2 * p + 1] - m2) * i2 * P_fg[2 * p + 1] + P_fb[2 * p + 1];
            pk[p] = (unsigned)f2bf(o0) | ((unsigned)f2bf(o1) << 16);
        }
        *reinterpret_cast<uint4*>(ybf + (((size_t)b * nT + (nT - 1)) * nL + l) * nD + d0) =
            make_uint4(pk[0], pk[1], pk[2], pk[3]);
    }
}

// scores from h via w2a; softmax over L; write scaled h as bf16; store probs
__global__ __launch_bounds__(256) void k_scores(
    const float* __restrict__ h, const float* __restrict__ w2a,
    const float* __restrict__ c2, const float* __restrict__ attn_b,
    unsigned short* __restrict__ hbf, float* __restrict__ scores)
{
    const int bt = blockIdx.x;
    const int tid = threadIdx.x, wid = tid >> 6, lane = tid & 63;
    __shared__ float slog[nL];
    const float* hrow = h + (size_t)bt * nLD;
    for (int l = wid; l < nL; l += 4) {
        const float* hp = hrow + l * nD;
        const float* wp = w2a + l * nD;
        float s = 0.f;
        for (int i = lane; i < nD; i += 64) s += hp[i] * wp[i];
#pragma unroll
        for (int off = 32; off > 0; off >>= 1) s += __shfl_down(s, off, 64);
        if (lane == 0) slog[l] = s + c2[l] + attn_b[0];
    }
    __syncthreads();
    float mx = -1e30f;
#pragma unroll
    for (int l = 0; l < nL; ++l) mx = fmaxf(mx, slog[l]);
    float den = 0.f;
#pragma unroll
    for (int l = 0; l < nL; ++l) den += __expf(slog[l] - mx);
    float rden = 1.f / den;
    unsigned short* obase = hbf + (size_t)bt * nLD;
#pragma unroll
    for (int it = 0; it < 4; ++it) {
        int idx = tid * 4 + it * 1024;
        int l = idx >> 9;
        float s = __expf(slog[l] - mx) * rden;
        float4 v = *reinterpret_cast<const float4*>(hrow + idx);
        unsigned p0 = (unsigned)f2bf(v.x * s) | ((unsigned)f2bf(v.y * s) << 16);
        unsigned p1 = (unsigned)f2bf(v.z * s) | ((unsigned)f2bf(v.w * s) << 16);
        *reinterpret_cast<uint2*>(obase + idx) = make_uint2(p0, p1);
    }
    if (tid < nL) scores[bt * nL + tid] = __expf(slog[tid] - mx) * rden;
}

// out = LN( wbuf + sum_l s_l * ff_b2[l] ) with ln_emb params
__global__ __launch_bounds__(256) void k_final(
    const float* __restrict__ wbuf, const float* __restrict__ scores,
    const float* __restrict__ ff_b2, const float* __restrict__ g,
    const float* __restrict__ bvec, float* __restrict__ out)
{
    const int bt = blockIdx.x;
    const int tid = threadIdx.x;
    __shared__ float ssc[nL];
    __shared__ float red[8];
    if (tid < nL) ssc[tid] = scores[bt * nL + tid];
    __syncthreads();
    const int e0 = tid * 4;
    float4 w = *reinterpret_cast<const float4*>(wbuf + (size_t)bt * nE + e0);
#pragma unroll
    for (int l = 0; l < nL; ++l) {
        float s = ssc[l];
        float4 b2 = *reinterpret_cast<const float4*>(ff_b2 + l * nE + e0);
        w.x += s * b2.x; w.y += s * b2.y; w.z += s * b2.z; w.w += s * b2.w;
    }
    float sum = w.x + w.y + w.z + w.w;
    float sq = w.x * w.x + w.y * w.y + w.z * w.z + w.w * w.w;
    int wid = tid >> 6, lane = tid & 63;
#pragma unroll
    for (int off = 32; off > 0; off >>= 1) {
        sum += __shfl_down(sum, off, 64); sq += __shfl_down(sq, off, 64);
    }
    if (lane == 0) { red[wid] = sum; red[4 + wid] = sq; }
    __syncthreads();
    sum = red[0] + red[1] + red[2] + red[3];
    sq  = red[4] + red[5] + red[6] + red[7];
    float mean = sum * (1.f / nE);
    float inv = rsqrtf(sq * (1.f / nE) - mean * mean + 1e-5f);
    float4 g4 = *reinterpret_cast<const float4*>(g + e0);
    float4 b4 = *reinterpret_cast<const float4*>(bvec + e0);
    float4 o;
    o.x = (w.x - mean) * inv * g4.x + b4.x;
    o.y = (w.y - mean) * inv * g4.y + b4.y;
    o.z = (w.z - mean) * inv * g4.z + b4.z;
    o.w = (w.w - mean) * inv * g4.w + b4.w;
    *reinterpret_cast<float4*>(out + (size_t)bt * nE + e0) = o;
}

extern "C" void kernel_launch(void* const* d_in, const int* in_sizes, int n_in,
                              void* d_out, int out_size, void* d_ws, size_t ws_size,
                              hipStream_t stream) {
    (void)in_sizes; (void)n_in; (void)out_size; (void)ws_size;
    const float* emb            = (const float*)d_in[0];
    const float* state_control  = (const float*)d_in[1];
    const float* input_influence= (const float*)d_in[2];
    const float* output_shaper  = (const float*)d_in[3];
    const float* glu_w          = (const float*)d_in[4];
    const float* glu_b          = (const float*)d_in[5];
    const float* e2s_w          = (const float*)d_in[6];
    const float* e2s_b          = (const float*)d_in[7];
    const float* ln_glu_g       = (const float*)d_in[8];
    const float* ln_glu_b       = (const float*)d_in[9];
    const float* ln_state_g     = (const float*)d_in[10];
    const float* ln_state_b     = (const float*)d_in[11];
    const float* ln_emb_g       = (const float*)d_in[12];
    const float* ln_emb_b       = (const float*)d_in[13];
    const float* ff_ln_g        = (const float*)d_in[14];
    const float* ff_ln_b        = (const float*)d_in[15];
    const float* ff_w1          = (const float*)d_in[16];
    const float* ff_b1          = (const float*)d_in[17];
    const float* ff_w2          = (const float*)d_in[18];
    const float* ff_b2          = (const float*)d_in[19];
    const float* attn_w         = (const float*)d_in[20];
    const float* attn_b         = (const float*)d_in[21];

    // workspace layout (~160 MB)
    char* ws = (char*)d_ws;
    float* tokens = (float*)ws;  ws += (size_t)nBT * nLD * 4;             // 67 MB
    float* vbuf   = (float*)ws;  ws += (size_t)nBT * nLD * 4;             // 67 MB
    uint4* wswz   = (uint4*)ws;  ws += (size_t)nL * 8 * 8 * 16 * 64 * 16; // 8 MB
    unsigned int* recs = (unsigned int*)ws; ws += (size_t)2 * nL * nB * 128 * 16;  // 256 KB
    unsigned short* w1T = (unsigned short*)ws; ws += (size_t)nL * nD * nD * 2;     // 4 MB
    unsigned short* w2T = (unsigned short*)ws; ws += (size_t)nE * nLD * 2;         // 8 MB
    float* sc_sum = (float*)ws;  ws += nLD * 4;
    float* ii_sum = (float*)ws;  ws += nLD * 4;
    float* os_sum = (float*)ws;  ws += nLD * 4;
    float* w2a    = (float*)ws;  ws += nLD * 4;
    float* c2     = (float*)ws;  ws += 256;
    float* scores = (float*)ws;  ws += (size_t)nBT * nL * 4;
    // aliases (lifetimes):
    unsigned short* emb_bf = (unsigned short*)vbuf;                    // dead before scan writes ybf
    unsigned short* e2sT   = (unsigned short*)vbuf + (size_t)nBT * nE; // ditto
    unsigned short* ybf    = (unsigned short*)vbuf;                    // scan out; dead after ff1
    float* hfull           = tokens;                                   // ff1 out (tokens dead after scan)
    unsigned short* hbf    = (unsigned short*)vbuf;                    // scores out (ybf dead)
    float* wbuf            = tokens;                                   // final GEMM out (h dead)

    // precompute
    k_init2<<<64, 256, 0, stream>>>(recs);
    k_pack2<<<nL * 64, 256, 0, stream>>>(glu_w, wswz);
    k_wdot<<<1024, 256, 0, stream>>>(state_control, nullptr, sc_sum, nLD, nD);
    k_wdot<<<1024, 256, 0, stream>>>(input_influence, nullptr, ii_sum, nLD, nD);
    k_wdot<<<1024, 256, 0, stream>>>(output_shaper, nullptr, os_sum, nLD, nD);
    k_wdot<<<1024, 256, 0, stream>>>(ff_w2, attn_w, w2a, nLD, nE);
    k_wdot<<<2, 256, 0, stream>>>(ff_b2, attn_w, c2, nL, nE);
    k_cast<<<nBT * nE / 1024, 256, 0, stream>>>(emb, emb_bf, nBT * nE);
    k_transp<<<dim3(nLD / 32, nE / 32, 1), 256, 0, stream>>>(e2s_w, e2sT, nE, nLD, 0, 0);
    k_transp<<<dim3(nD / 32, nD / 32, nL), 256, 0, stream>>>(ff_w1, w1T, nD, nD,
                                                             (long long)nD * nD, (long long)nD * nD);
    k_transp<<<dim3(nE / 32, nLD / 32, 1), 256, 0, stream>>>(ff_w2, w2T, nLD, nE, 0, 0);

    // tokens = emb @ e2s_w + e2s_b   [4096 x 4096], K=1024  (bf16 MFMA)
    k_gemm_bf<0><<<dim3(32, 32, 1), 256, 0, stream>>>(
        emb_bf, nE, 0, e2sT, nE, 0, e2s_b, 0, tokens, nLD, 0, nBT, nLD, nE);

    // distributed recurrent scan -> ybf (y = LN_ff(LN_state(v)*os), fused)
    k_scan8<<<64, 512, 0, stream>>>(tokens, wswz, glu_b, sc_sum, ii_sum, os_sum,
                                    ln_glu_g, ln_glu_b, ln_state_g, ln_state_b,
                                    ff_ln_g, ff_ln_b, ybf, recs);

    // h = GELU(y @ ff_w1 + ff_b1), per-layer batched (bf16 MFMA) -> hfull
    k_gemm_bf<1><<<dim3(4, 32, 8), 256, 0, stream>>>(
        ybf, nLD, nD, w1T, nD, (long long)nD * nD, ff_b1, nD,
        hfull, nLD, nD, nBT, nD, nD);

    // scores; scaled h -> bf16 hbf
    k_scores<<<nBT, 256, 0, stream>>>(hfull, w2a, c2, attn_b, hbf, scores);

    // weighted = (s*h) @ W2cat   [4096 x 1024], K=4096 (bf16 MFMA) -> wbuf
    k_gemm_bf<0><<<dim3(8, 32, 1), 256, 0, stream>>>(
        hbf, nLD, 0, w2T, nLD, 0, nullptr, 0, wbuf, nE, 0, nBT, nE, nLD);

    // out = LN(weighted + sum_l s_l*ff_b2[l])
    k_final<<<nBT, 256, 0, stream>>>(wbuf, scores, ff_b2, ln_emb_g, ln_emb_b, (float*)d_out);
}

// Round 14
// 1939.110 us; speedup vs baseline: 1.1260x; 1.0098x over previous
//
#include <hip/hip_runtime.h>
#include <hip/hip_bf16.h>
#include <math.h>

// Fixed problem dims
static constexpr int nB = 8, nT = 512, nE = 1024, nL = 8, nD = 512;
static constexpr int nBT = nB * nT;   // 4096 rows (b,t)
static constexpr int nLD = nL * nD;   // 4096

typedef __attribute__((ext_vector_type(8))) short short8v;  // 8 bf16 (4 VGPRs)
typedef __attribute__((ext_vector_type(4))) float f32x4;
typedef __attribute__((ext_vector_type(4))) unsigned int u32x4;  // asm-safe

__device__ __forceinline__ unsigned short f2bf(float f) {
    unsigned int u = __float_as_uint(f);
    return (unsigned short)((u + 0x7fffu + ((u >> 16) & 1u)) >> 16);  // RNE
}
__device__ __forceinline__ float bfu2f(unsigned short u) {
    return __uint_as_float(((unsigned int)u) << 16);
}
__device__ __forceinline__ float gelu_f(float x) {
    return 0.5f * x * (1.0f + erff(x * 0.70710678118654752f));  // exact GELU
}

// dst[r] = sum_i src[r,i] * (w ? w[i] : 1)
__global__ __launch_bounds__(256) void k_wdot(const float* __restrict__ src,
                                              const float* __restrict__ w,
                                              float* __restrict__ dst,
                                              int rows, int rowlen) {
    int row = blockIdx.x * 4 + (threadIdx.x >> 6);
    if (row >= rows) return;
    int lane = threadIdx.x & 63;
    const float* p = src + (size_t)row * rowlen;
    float s = 0.f;
    if (w) { for (int i = lane; i < rowlen; i += 64) s += p[i] * w[i]; }
    else   { for (int i = lane; i < rowlen; i += 64) s += p[i]; }
#pragma unroll
    for (int off = 32; off > 0; off >>= 1) s += __shfl_down(s, off, 64);
    if (lane == 0) dst[row] = s;
}

// zero all record tags (must run each launch: stale tags from the previous
// timed replay alias valid step numbers)
__global__ __launch_bounds__(256) void k_init2(unsigned int* recs) {
    int i = blockIdx.x * 256 + threadIdx.x;   // 16384 records
    if (i < 2 * nL * nB * 128)
        __hip_atomic_store(recs + i * 4 + 3, 0u,
                           __ATOMIC_RELAXED, __HIP_MEMORY_SCOPE_AGENT);
}

// flat fp32 -> bf16 cast
__global__ __launch_bounds__(256) void k_cast(const float* __restrict__ s,
                                              unsigned short* __restrict__ d, int n) {
    int idx = (blockIdx.x * 256 + threadIdx.x) * 4;
    if (idx >= n) return;
    float4 v = *reinterpret_cast<const float4*>(s + idx);
    ushort4 o;
    o.x = f2bf(v.x); o.y = f2bf(v.y); o.z = f2bf(v.z); o.w = f2bf(v.w);
    *reinterpret_cast<ushort4*>(d + idx) = o;
}

// tiled transpose-cast: dst[c][r] (bf16) = src[r][c] (fp32); batch via z
__global__ __launch_bounds__(256) void k_transp(const float* __restrict__ src,
                                                unsigned short* __restrict__ dst,
                                                int R, int Cc,
                                                long long sSrc, long long sDst) {
    src += (size_t)blockIdx.z * sSrc;
    dst += (size_t)blockIdx.z * sDst;
    __shared__ float t[32][33];
    const int tx = threadIdx.x & 31, ty = threadIdx.x >> 5;  // ty 0..7
    const int r0 = blockIdx.y * 32, c0 = blockIdx.x * 32;
#pragma unroll
    for (int r = 0; r < 4; ++r)
        t[ty + r * 8][tx] = src[(size_t)(r0 + ty + r * 8) * Cc + c0 + tx];
    __syncthreads();
#pragma unroll
    for (int r = 0; r < 4; ++r)
        dst[(size_t)(c0 + ty + r * 8) * R + r0 + tx] = f2bf(t[tx][ty + r * 8]);
}

// Pack glu_w into MFMA B-fragment layout with INTERLEAVED a/g columns.
__global__ __launch_bounds__(256) void k_pack2(const float* __restrict__ src,
                                               uint4* __restrict__ dst) {
    const int blk = blockIdx.x;            // l*64 + q*8 + w   (512 blocks)
    const int w = blk & 7, q = (blk >> 3) & 7, l = blk >> 6;
    const float* wl = src + (size_t)l * nD * 1024;
    for (int i = threadIdx.x; i < 16 * 64; i += 256) {
        const int kt = i >> 6, ln = i & 63;
        const int j = ln & 15, g = ln >> 4;
        const int u = j >> 1;
        const int col = (j & 1) ? (512 + q * 64 + w * 8 + u)
                                : (q * 64 + w * 8 + u);
        const int k0 = 32 * kt + 8 * g;
        unsigned pr[4];
#pragma unroll
        for (int p = 0; p < 4; ++p) {
            float a = wl[(size_t)(k0 + 2 * p) * 1024 + col];
            float c = wl[(size_t)(k0 + 2 * p + 1) * 1024 + col];
            pr[p] = (unsigned)f2bf(a) | ((unsigned)f2bf(c) << 16);
        }
        dst[((((size_t)l * 8 + q) * 8 + w) * 16 + kt) * 64 + ln] =
            make_uint4(pr[0], pr[1], pr[2], pr[3]);
    }
}

// ---------------------------------------------------------------------------
// bf16 MFMA GEMM, software-pipelined (R13). Supports split-K via blockIdx.z
// with per-z offsets sA/sB (elements) and sC (C buffer stride).
// ---------------------------------------------------------------------------
template<int ACT>
__global__ __launch_bounds__(256) void k_gemm_bf(
    const unsigned short* __restrict__ A, int lda, long long sA,
    const unsigned short* __restrict__ Bt, int ldb, long long sB,
    const float* __restrict__ bias, long long sBias,
    float* __restrict__ C, int ldc, long long sC,
    int M, int N, int K)
{
    A  += (size_t)blockIdx.z * sA;
    Bt += (size_t)blockIdx.z * sB;
    C  += (size_t)blockIdx.z * sC;
    const float* biasp = bias ? bias + (size_t)blockIdx.z * sBias : nullptr;

    __shared__ __align__(16) unsigned short A_s[128][40];
    __shared__ __align__(16) unsigned short B_s[128][40];
    const int tid = threadIdx.x, lane = tid & 63;
    const int wv = tid >> 6;
    const int wm = (wv >> 1) * 64, wn = (wv & 1) * 64;
    const int bm = blockIdx.y * 128, bn = blockIdx.x * 128;
    const int srow = tid >> 2, sc8 = (tid & 3) * 8;

    f32x4 acc[4][4];
#pragma unroll
    for (int i = 0; i < 4; ++i)
#pragma unroll
        for (int j = 0; j < 4; ++j) acc[i][j] = f32x4{0.f, 0.f, 0.f, 0.f};

    const int fr = lane & 15, fg = (lane >> 4) * 8;

    const unsigned short* pA0 = A + (size_t)(bm + srow) * lda + sc8;
    const unsigned short* pA1 = A + (size_t)(bm + srow + 64) * lda + sc8;
    const unsigned short* pB0 = Bt + (size_t)(bn + srow) * ldb + sc8;
    const unsigned short* pB1 = Bt + (size_t)(bn + srow + 64) * ldb + sc8;

    uint4 a0 = *reinterpret_cast<const uint4*>(pA0);
    uint4 a1 = *reinterpret_cast<const uint4*>(pA1);
    uint4 b0 = *reinterpret_cast<const uint4*>(pB0);
    uint4 b1 = *reinterpret_cast<const uint4*>(pB1);

    for (int kt = 0; kt < K; kt += 32) {
        __syncthreads();  // prior compute done before overwriting LDS
        *reinterpret_cast<uint4*>(&A_s[srow][sc8]) = a0;
        *reinterpret_cast<uint4*>(&A_s[srow + 64][sc8]) = a1;
        *reinterpret_cast<uint4*>(&B_s[srow][sc8]) = b0;
        *reinterpret_cast<uint4*>(&B_s[srow + 64][sc8]) = b1;
        __syncthreads();

        const bool more = (kt + 32 < K);
        if (more) {  // issue next tile's loads; they fly during MFMA below
            a0 = *reinterpret_cast<const uint4*>(pA0 + kt + 32);
            a1 = *reinterpret_cast<const uint4*>(pA1 + kt + 32);
            b0 = *reinterpret_cast<const uint4*>(pB0 + kt + 32);
            b1 = *reinterpret_cast<const uint4*>(pB1 + kt + 32);
        }

        short8v af[4], bf[4];
#pragma unroll
        for (int mi = 0; mi < 4; ++mi)
            af[mi] = *reinterpret_cast<const short8v*>(&A_s[wm + mi * 16 + fr][fg]);
#pragma unroll
        for (int ni = 0; ni < 4; ++ni)
            bf[ni] = *reinterpret_cast<const short8v*>(&B_s[wn + ni * 16 + fr][fg]);
#pragma unroll
        for (int mi = 0; mi < 4; ++mi)
#pragma unroll
            for (int ni = 0; ni < 4; ++ni)
                acc[mi][ni] = __builtin_amdgcn_mfma_f32_16x16x32_bf16(
                    af[mi], bf[ni], acc[mi][ni], 0, 0, 0);
    }

#pragma unroll
    for (int mi = 0; mi < 4; ++mi)
#pragma unroll
        for (int ni = 0; ni < 4; ++ni) {
            const int col = bn + wn + ni * 16 + (lane & 15);
            const float bv = biasp ? biasp[col] : 0.f;
#pragma unroll
            for (int p = 0; p < 4; ++p) {
                const int row = bm + wm + mi * 16 + (lane >> 4) * 4 + p;
                float v = acc[mi][ni][p] + bv;
                if (ACT == 1) v = gelu_f(v);
                C[(size_t)row * ldc + col] = v;
            }
        }
}

// ---------------------------------------------------------------------------
// Scan (R13 structure) + s_sleep backoff in poll loops (tail mitigation).
// ---------------------------------------------------------------------------
__global__ __launch_bounds__(512, 1) void k_scan8(
    const float* __restrict__ tokens,      // [B,T,L,D]
    const uint4* __restrict__ wswz,        // packed B-fragments (interleaved)
    const float* __restrict__ glu_b,       // [L,2D]
    const float* __restrict__ sc_sum, const float* __restrict__ ii_sum,
    const float* __restrict__ os_sum,      // [L,D]
    const float* __restrict__ ln_glu_g, const float* __restrict__ ln_glu_b,
    const float* __restrict__ ln_state_g, const float* __restrict__ ln_state_b,
    const float* __restrict__ ff_ln_g, const float* __restrict__ ff_ln_b,  // [L,D]
    unsigned short* __restrict__ ybf,      // [B,T,L,D] bf16 y output
    unsigned int* __restrict__ recs)
{
    const int l = blockIdx.x & 7, q = blockIdx.x >> 3;
    const int tid = threadIdx.x, w = tid >> 6, lane = tid & 63;
    const int b = w;  // wave = batch

    __shared__ __align__(16) unsigned hn_pk[8][260];       // bf16 pairs, padded
    __shared__ __align__(16) unsigned zbuf[4];
    __shared__ __align__(16) unsigned short vrow[8][512];  // consumer v (bf16)
    __shared__ __align__(16) unsigned short vstage[8][64]; // producer stage
    __shared__ __align__(16) float vsq[8][8][2];           // [b][w]{S,Q}

    uint4 wr[16];
    {
        const uint4* wp = wswz + ((((size_t)l * 8 + q) * 8 + w) * 16) * 64 + lane;
#pragma unroll
        for (int kt = 0; kt < 16; ++kt) wr[kt] = wp[kt * 64];
    }
    const int d0 = lane * 8;
    float P_sc[8], P_ii[8], P_gg[8], P_gb[8], P_sg[8], P_sb[8];
    float P_os[8], P_fg[8], P_fb[8];
#pragma unroll
    for (int j = 0; j < 8; j += 4) {
        *reinterpret_cast<float4*>(&P_sc[j]) = *reinterpret_cast<const float4*>(sc_sum + l * nD + d0 + j);
        *reinterpret_cast<float4*>(&P_ii[j]) = *reinterpret_cast<const float4*>(ii_sum + l * nD + d0 + j);
        *reinterpret_cast<float4*>(&P_os[j]) = *reinterpret_cast<const float4*>(os_sum + l * nD + d0 + j);
        *reinterpret_cast<float4*>(&P_gg[j]) = *reinterpret_cast<const float4*>(ln_glu_g + d0 + j);
        *reinterpret_cast<float4*>(&P_gb[j]) = *reinterpret_cast<const float4*>(ln_glu_b + d0 + j);
        *reinterpret_cast<float4*>(&P_sg[j]) = *reinterpret_cast<const float4*>(ln_state_g + d0 + j);
        *reinterpret_cast<float4*>(&P_sb[j]) = *reinterpret_cast<const float4*>(ln_state_b + d0 + j);
        *reinterpret_cast<float4*>(&P_fg[j]) = *reinterpret_cast<const float4*>(ff_ln_g + l * nD + d0 + j);
        *reinterpret_cast<float4*>(&P_fb[j]) = *reinterpret_cast<const float4*>(ff_ln_b + l * nD + d0 + j);
    }
    const int cu = (lane & 15) >> 1;
    const int mycol = (lane & 1) ? (512 + q * 64 + w * 8 + cu)
                                 : (q * 64 + w * 8 + cu);
    const float bias_c = glu_b[l * 1024 + mycol];

    if (tid < 4) zbuf[tid] = 0u;

    const float* tokp = tokens + ((size_t)b * nT * nL + l) * nD + d0;

    const unsigned* afp; int astep;
    {
        int bb = lane & 15, g = lane >> 4;
        if (bb < 8) { afp = &hn_pk[bb][g * 4]; astep = 16; }
        else        { afp = &zbuf[0];          astep = 0;  }
    }
    __syncthreads();

    float4 tk0 = *reinterpret_cast<const float4*>(tokp);
    float4 tk1 = *reinterpret_cast<const float4*>(tokp + 4);

    float stC[8];   // cached LN_state(v[t-1]) for the y-fold

    for (int t = 0; t < nT; ++t) {
        float tk[8] = {tk0.x, tk0.y, tk0.z, tk0.w, tk1.x, tk1.y, tk1.z, tk1.w};
        float h[8];
        if (t > 0) {
            const unsigned* rp = recs + ((((size_t)((t - 1) & 1) * nL + l) * nB + b) * 128) * 4;
            const unsigned* pa = rp + lane * 4;
            const unsigned* pb = rp + (lane + 64) * 4;
            u32x4 ra, rb;
            for (;;) {
                asm volatile(
                    "global_load_dwordx4 %0, %2, off sc0 sc1\n\t"
                    "global_load_dwordx4 %1, %3, off sc0 sc1\n\t"
                    "s_waitcnt vmcnt(0)"
                    : "=&v"(ra), "=&v"(rb)
                    : "v"(pa), "v"(pb)
                    : "memory");
                int ok = (ra[3] == (unsigned)t) && (rb[3] == (unsigned)t);
                if (__all(ok)) break;
                __builtin_amdgcn_s_sleep(1);   // back off: unthrottled spins
            }                                  // caused rare 20x tail stalls

            float S = 0.f, Q = 0.f;
            if (lane & 1) {
                S = __uint_as_float(ra[1]) + __uint_as_float(rb[1]);
                Q = __uint_as_float(ra[2]) + __uint_as_float(rb[2]);
            }
#pragma unroll
            for (int o = 32; o > 0; o >>= 1) { S += __shfl_xor(S, o, 64); Q += __shfl_xor(Q, o, 64); }
            const float mv = S * (1.f / nD);
            const float iv = rsqrtf(Q * (1.f / nD) - mv * mv + 1e-5f);

            {
                const int ia = lane, ib2 = lane + 64;
                const int qa = ia >> 4, wa = (ia >> 1) & 7, ja = ia & 1;
                const int qb2 = ib2 >> 4, wb2 = (ib2 >> 1) & 7;
                unsigned* da = reinterpret_cast<unsigned*>(&vrow[b][qa * 64 + wa * 8 + ja * 6]);
                unsigned* db = reinterpret_cast<unsigned*>(&vrow[b][qb2 * 64 + wb2 * 8 + ja * 6]);
                if (!ja) {
                    da[0] = ra[0]; da[1] = ra[1]; da[2] = ra[2];
                    db[0] = rb[0]; db[1] = rb[1]; db[2] = rb[2];
                } else {
                    da[0] = ra[0];
                    db[0] = rb[0];
                }
            }
            asm volatile("s_waitcnt lgkmcnt(0)" ::: "memory");
            __builtin_amdgcn_sched_barrier(0);
            uint4 pv = *reinterpret_cast<const uint4*>(&vrow[b][lane * 8]);
            float vv[8];
            vv[0] = bfu2f((unsigned short)(pv.x & 0xffffu));
            vv[1] = bfu2f((unsigned short)(pv.x >> 16));
            vv[2] = bfu2f((unsigned short)(pv.y & 0xffffu));
            vv[3] = bfu2f((unsigned short)(pv.y >> 16));
            vv[4] = bfu2f((unsigned short)(pv.z & 0xffffu));
            vv[5] = bfu2f((unsigned short)(pv.z >> 16));
            vv[6] = bfu2f((unsigned short)(pv.w & 0xffffu));
            vv[7] = bfu2f((unsigned short)(pv.w >> 16));
#pragma unroll
            for (int j = 0; j < 8; ++j) {
                stC[j] = (vv[j] - mv) * iv * P_sg[j] + P_sb[j];
                h[j] = stC[j] * P_sc[j] + tk[j] * P_ii[j];
            }
        } else {
#pragma unroll
            for (int j = 0; j < 8; ++j) h[j] = tk[j] * P_ii[j];
        }

        if (t + 1 < nT) {
            tk0 = *reinterpret_cast<const float4*>(tokp + (size_t)(t + 1) * nLD);
            tk1 = *reinterpret_cast<const float4*>(tokp + (size_t)(t + 1) * nLD + 4);
        }

        float S = 0.f, Q = 0.f;
#pragma unroll
        for (int j = 0; j < 8; ++j) { S += h[j]; Q += h[j] * h[j]; }
#pragma unroll
        for (int o = 32; o > 0; o >>= 1) { S += __shfl_xor(S, o, 64); Q += __shfl_xor(Q, o, 64); }
        const float mh = S * (1.f / nD);
        const float ih = rsqrtf(Q * (1.f / nD) - mh * mh + 1e-5f);
        unsigned pr[4];
#pragma unroll
        for (int p = 0; p < 4; ++p) {
            float a0 = (h[2 * p]     - mh) * ih * P_gg[2 * p]     + P_gb[2 * p];
            float a1 = (h[2 * p + 1] - mh) * ih * P_gg[2 * p + 1] + P_gb[2 * p + 1];
            pr[p] = (unsigned)f2bf(a0) | ((unsigned)f2bf(a1) << 16);
        }
        *reinterpret_cast<uint4*>(&hn_pk[b][lane * 4]) = make_uint4(pr[0], pr[1], pr[2], pr[3]);

        asm volatile("s_waitcnt lgkmcnt(0)" ::: "memory");
        __builtin_amdgcn_s_barrier();
        __builtin_amdgcn_sched_barrier(0);

        f32x4 acc0 = {0.f, 0.f, 0.f, 0.f}, acc1 = {0.f, 0.f, 0.f, 0.f};
#pragma unroll
        for (int kt = 0; kt < 8; ++kt) {
            short8v a0 = *reinterpret_cast<const short8v*>(afp + (2 * kt) * astep);
            short8v a1 = *reinterpret_cast<const short8v*>(afp + (2 * kt + 1) * astep);
            acc0 = __builtin_amdgcn_mfma_f32_16x16x32_bf16(
                a0, __builtin_bit_cast(short8v, wr[2 * kt]), acc0, 0, 0, 0);
            acc1 = __builtin_amdgcn_mfma_f32_16x16x32_bf16(
                a1, __builtin_bit_cast(short8v, wr[2 * kt + 1]), acc1, 0, 0, 0);
        }

        float x[4], y[4];
#pragma unroll
        for (int i = 0; i < 4; ++i) x[i] = acc0[i] + acc1[i] + bias_c;
#pragma unroll
        for (int i = 0; i < 4; ++i) y[i] = __shfl_xor(x[i], 1, 64);
        float sv[4], sq[4];
        const int r0 = (lane >> 4) * 4;
        const bool prod = (lane < 32) && !(lane & 1);
#pragma unroll
        for (int i = 0; i < 4; ++i) {
            float v = x[i] / (1.f + __expf(-y[i]));
            sv[i] = prod ? v : 0.f;
            sq[i] = prod ? v * v : 0.f;
            if (prod) vstage[r0 + i][w * 8 + cu] = f2bf(v);
        }
#pragma unroll
        for (int i = 0; i < 4; ++i) {
            sv[i] += __shfl_xor(sv[i], 2, 64); sq[i] += __shfl_xor(sq[i], 2, 64);
            sv[i] += __shfl_xor(sv[i], 4, 64); sq[i] += __shfl_xor(sq[i], 4, 64);
            sv[i] += __shfl_xor(sv[i], 8, 64); sq[i] += __shfl_xor(sq[i], 8, 64);
        }
        if (lane == 0 || lane == 16) {
#pragma unroll
            for (int i = 0; i < 4; ++i) {
                vsq[r0 + i][w][0] = sv[i];
                vsq[r0 + i][w][1] = sq[i];
            }
        }

        asm volatile("s_waitcnt lgkmcnt(0)" ::: "memory");
        __builtin_amdgcn_s_barrier();
        __builtin_amdgcn_sched_barrier(0);

        if (tid < 128) {
            const int bb = tid >> 4, wb = (tid >> 1) & 7, jb = tid & 1;
            const unsigned* vp = reinterpret_cast<const unsigned*>(&vstage[bb][wb * 8]);
            u32x4 rec;
            if (!jb) { rec[0] = vp[0]; rec[1] = vp[1]; rec[2] = vp[2]; }
            else {
                rec[0] = vp[3];
                rec[1] = __float_as_uint(vsq[bb][wb][0]);
                rec[2] = __float_as_uint(vsq[bb][wb][1]);
            }
            rec[3] = (unsigned)(t + 1);
            unsigned* dst = recs + (((((size_t)(t & 1) * nL + l) * nB + bb) * 128)
                                    + q * 16 + wb * 2 + jb) * 4;
            asm volatile("global_store_dwordx4 %0, %1, off sc0 sc1"
                         :: "v"(dst), "v"(rec) : "memory");
        }

        // ---- fused y[t-1] from cached stC (hidden in publish->poll window) ----
        if (t > 0) {
            float val[8], S2 = 0.f, Q2 = 0.f;
#pragma unroll
            for (int j = 0; j < 8; ++j) {
                val[j] = stC[j] * P_os[j];
                S2 += val[j]; Q2 += val[j] * val[j];
            }
#pragma unroll
            for (int o = 32; o > 0; o >>= 1) { S2 += __shfl_xor(S2, o, 64); Q2 += __shfl_xor(Q2, o, 64); }
            const float m2 = S2 * (1.f / nD);
            const float i2 = rsqrtf(Q2 * (1.f / nD) - m2 * m2 + 1e-5f);
            unsigned pk[4];
#pragma unroll
            for (int p = 0; p < 4; ++p) {
                float o0 = (val[2 * p]     - m2) * i2 * P_fg[2 * p]     + P_fb[2 * p];
                float o1 = (val[2 * p + 1] - m2) * i2 * P_fg[2 * p + 1] + P_fb[2 * p + 1];
                pk[p] = (unsigned)f2bf(o0) | ((unsigned)f2bf(o1) << 16);
            }
            *reinterpret_cast<uint4*>(ybf + (((size_t)b * nT + (t - 1)) * nL + l) * nD + d0) =
                make_uint4(pk[0], pk[1], pk[2], pk[3]);
        }
    }

    // ---- epilogue: y[nT-1] from the final records (tag nT) ----
    {
        const unsigned tagf = (unsigned)nT;
        const unsigned* rp = recs + ((((size_t)((nT - 1) & 1) * nL + l) * nB + b) * 128) * 4;
        const unsigned* pa = rp + lane * 4;
        const unsigned* pb = rp + (lane + 64) * 4;
        u32x4 ra, rb;
        for (;;) {
            asm volatile(
                "global_load_dwordx4 %0, %2, off sc0 sc1\n\t"
                "global_load_dwordx4 %1, %3, off sc0 sc1\n\t"
                "s_waitcnt vmcnt(0)"
                : "=&v"(ra), "=&v"(rb)
                : "v"(pa), "v"(pb)
                : "memory");
            int ok = (ra[3] == tagf) && (rb[3] == tagf);
            if (__all(ok)) break;
            __builtin_amdgcn_s_sleep(1);
        }

        float S = 0.f, Q = 0.f;
        if (lane & 1) {
            S = __uint_as_float(ra[1]) + __uint_as_float(rb[1]);
            Q = __uint_as_float(ra[2]) + __uint_as_float(rb[2]);
        }
#pragma unroll
        for (int o = 32; o > 0; o >>= 1) { S += __shfl_xor(S, o, 64); Q += __shfl_xor(Q, o, 64); }
        const float mv = S * (1.f / nD);
        const float iv = rsqrtf(Q * (1.f / nD) - mv * mv + 1e-5f);
        {
            const int ia = lane, ib2 = lane + 64;
            const int qa = ia >> 4, wa = (ia >> 1) & 7, ja = ia & 1;
            const int qb2 = ib2 >> 4, wb2 = (ib2 >> 1) & 7;
            unsigned* da = reinterpret_cast<unsigned*>(&vrow[b][qa * 64 + wa * 8 + ja * 6]);
            unsigned* db = reinterpret_cast<unsigned*>(&vrow[b][qb2 * 64 + wb2 * 8 + ja * 6]);
            if (!ja) {
                da[0] = ra[0]; da[1] = ra[1]; da[2] = ra[2];
                db[0] = rb[0]; db[1] = rb[1]; db[2] = rb[2];
            } else {
                da[0] = ra[0];
                db[0] = rb[0];
            }
        }
        asm volatile("s_waitcnt lgkmcnt(0)" ::: "memory");
        __builtin_amdgcn_sched_barrier(0);
        uint4 pv = *reinterpret_cast<const uint4*>(&vrow[b][lane * 8]);
        float vv[8];
        vv[0] = bfu2f((unsigned short)(pv.x & 0xffffu));
        vv[1] = bfu2f((unsigned short)(pv.x >> 16));
        vv[2] = bfu2f((unsigned short)(pv.y & 0xffffu));
        vv[3] = bfu2f((unsigned short)(pv.y >> 16));
        vv[4] = bfu2f((unsigned short)(pv.z & 0xffffu));
        vv[5] = bfu2f((unsigned short)(pv.z >> 16));
        vv[6] = bfu2f((unsigned short)(pv.w & 0xffffu));
        vv[7] = bfu2f((unsigned short)(pv.w >> 16));
        float val[8], S2 = 0.f, Q2 = 0.f;
#pragma unroll
        for (int j = 0; j < 8; ++j) {
            float st = (vv[j] - mv) * iv * P_sg[j] + P_sb[j];
            val[j] = st * P_os[j];
            S2 += val[j]; Q2 += val[j] * val[j];
        }
#pragma unroll
        for (int o = 32; o > 0; o >>= 1) { S2 += __shfl_xor(S2, o, 64); Q2 += __shfl_xor(Q2, o, 64); }
        const float m2 = S2 * (1.f / nD);
        const float i2 = rsqrtf(Q2 * (1.f / nD) - m2 * m2 + 1e-5f);
        unsigned pk[4];
#pragma unroll
        for (int p = 0; p < 4; ++p) {
            float o0 = (val[2 * p]     - m2) * i2 * P_fg[2 * p]     + P_fb[2 * p];
            float o1 = (val[2 * p + 1] - m2) * i2 * P_fg[2 * p + 1] + P_fb[2 * p + 1];
            pk[p] = (unsigned)f2bf(o0) | ((unsigned)f2bf(o1) << 16);
        }
        *reinterpret_cast<uint4*>(ybf + (((size_t)b * nT + (nT - 1)) * nL + l) * nD + d0) =
            make_uint4(pk[0], pk[1], pk[2], pk[3]);
    }
}

// scores from h via w2a; softmax over L; write scaled h as bf16; store probs
__global__ __launch_bounds__(256) void k_scores(
    const float* __restrict__ h, const float* __restrict__ w2a,
    const float* __restrict__ c2, const float* __restrict__ attn_b,
    unsigned short* __restrict__ hbf, float* __restrict__ scores)
{
    const int bt = blockIdx.x;
    const int tid = threadIdx.x, wid = tid >> 6, lane = tid & 63;
    __shared__ float slog[nL];
    const float* hrow = h + (size_t)bt * nLD;
    for (int l = wid; l < nL; l += 4) {
        const float* hp = hrow + l * nD;
        const float* wp = w2a + l * nD;
        float s = 0.f;
        for (int i = lane; i < nD; i += 64) s += hp[i] * wp[i];
#pragma unroll
        for (int off = 32; off > 0; off >>= 1) s += __shfl_down(s, off, 64);
        if (lane == 0) slog[l] = s + c2[l] + attn_b[0];
    }
    __syncthreads();
    float mx = -1e30f;
#pragma unroll
    for (int l = 0; l < nL; ++l) mx = fmaxf(mx, slog[l]);
    float den = 0.f;
#pragma unroll
    for (int l = 0; l < nL; ++l) den += __expf(slog[l] - mx);
    float rden = 1.f / den;
    unsigned short* obase = hbf + (size_t)bt * nLD;
#pragma unroll
    for (int it = 0; it < 4; ++it) {
        int idx = tid * 4 + it * 1024;
        int l = idx >> 9;
        float s = __expf(slog[l] - mx) * rden;
        float4 v = *reinterpret_cast<const float4*>(hrow + idx);
        unsigned p0 = (unsigned)f2bf(v.x * s) | ((unsigned)f2bf(v.y * s) << 16);
        unsigned p1 = (unsigned)f2bf(v.z * s) | ((unsigned)f2bf(v.w * s) << 16);
        *reinterpret_cast<uint2*>(obase + idx) = make_uint2(p0, p1);
    }
    if (tid < nL) scores[bt * nL + tid] = __expf(slog[tid] - mx) * rden;
}

// out = LN( wbufA + wbufB + sum_l s_l * ff_b2[l] )  (split-K partials summed)
__global__ __launch_bounds__(256) void k_final(
    const float* __restrict__ wbufA, const float* __restrict__ wbufB,
    const float* __restrict__ scores,
    const float* __restrict__ ff_b2, const float* __restrict__ g,
    const float* __restrict__ bvec, float* __restrict__ out)
{
    const int bt = blockIdx.x;
    const int tid = threadIdx.x;
    __shared__ float ssc[nL];
    __shared__ float red[8];
    if (tid < nL) ssc[tid] = scores[bt * nL + tid];
    __syncthreads();
    const int e0 = tid * 4;
    float4 w = *reinterpret_cast<const float4*>(wbufA + (size_t)bt * nE + e0);
    float4 w2 = *reinterpret_cast<const float4*>(wbufB + (size_t)bt * nE + e0);
    w.x += w2.x; w.y += w2.y; w.z += w2.z; w.w += w2.w;
#pragma unroll
    for (int l = 0; l < nL; ++l) {
        float s = ssc[l];
        float4 b2 = *reinterpret_cast<const float4*>(ff_b2 + l * nE + e0);
        w.x += s * b2.x; w.y += s * b2.y; w.z += s * b2.z; w.w += s * b2.w;
    }
    float sum = w.x + w.y + w.z + w.w;
    float sq = w.x * w.x + w.y * w.y + w.z * w.z + w.w * w.w;
    int wid = tid >> 6, lane = tid & 63;
#pragma unroll
    for (int off = 32; off > 0; off >>= 1) {
        sum += __shfl_down(sum, off, 64); sq += __shfl_down(sq, off, 64);
    }
    if (lane == 0) { red[wid] = sum; red[4 + wid] = sq; }
    __syncthreads();
    sum = red[0] + red[1] + red[2] + red[3];
    sq  = red[4] + red[5] + red[6] + red[7];
    float mean = sum * (1.f / nE);
    float inv = rsqrtf(sq * (1.f / nE) - mean * mean + 1e-5f);
    float4 g4 = *reinterpret_cast<const float4*>(g + e0);
    float4 b4 = *reinterpret_cast<const float4*>(bvec + e0);
    float4 o;
    o.x = (w.x - mean) * inv * g4.x + b4.x;
    o.y = (w.y - mean) * inv * g4.y + b4.y;
    o.z = (w.z - mean) * inv * g4.z + b4.z;
    o.w = (w.w - mean) * inv * g4.w + b4.w;
    *reinterpret_cast<float4*>(out + (size_t)bt * nE + e0) = o;
}

extern "C" void kernel_launch(void* const* d_in, const int* in_sizes, int n_in,
                              void* d_out, int out_size, void* d_ws, size_t ws_size,
                              hipStream_t stream) {
    (void)in_sizes; (void)n_in; (void)out_size; (void)ws_size;
    const float* emb            = (const float*)d_in[0];
    const float* state_control  = (const float*)d_in[1];
    const float* input_influence= (const float*)d_in[2];
    const float* output_shaper  = (const float*)d_in[3];
    const float* glu_w          = (const float*)d_in[4];
    const float* glu_b          = (const float*)d_in[5];
    const float* e2s_w          = (const float*)d_in[6];
    const float* e2s_b          = (const float*)d_in[7];
    const float* ln_glu_g       = (const float*)d_in[8];
    const float* ln_glu_b       = (const float*)d_in[9];
    const float* ln_state_g     = (const float*)d_in[10];
    const float* ln_state_b     = (const float*)d_in[11];
    const float* ln_emb_g       = (const float*)d_in[12];
    const float* ln_emb_b       = (const float*)d_in[13];
    const float* ff_ln_g        = (const float*)d_in[14];
    const float* ff_ln_b        = (const float*)d_in[15];
    const float* ff_w1          = (const float*)d_in[16];
    const float* ff_b1          = (const float*)d_in[17];
    const float* ff_w2          = (const float*)d_in[18];
    const float* ff_b2          = (const float*)d_in[19];
    const float* attn_w         = (const float*)d_in[20];
    const float* attn_b         = (const float*)d_in[21];

    // workspace layout (~160 MB)
    char* ws = (char*)d_ws;
    float* tokens = (float*)ws;  ws += (size_t)nBT * nLD * 4;             // 67 MB
    float* vbuf   = (float*)ws;  ws += (size_t)nBT * nLD * 4;             // 67 MB
    uint4* wswz   = (uint4*)ws;  ws += (size_t)nL * 8 * 8 * 16 * 64 * 16; // 8 MB
    unsigned int* recs = (unsigned int*)ws; ws += (size_t)2 * nL * nB * 128 * 16;  // 256 KB
    unsigned short* w1T = (unsigned short*)ws; ws += (size_t)nL * nD * nD * 2;     // 4 MB
    unsigned short* w2T = (unsigned short*)ws; ws += (size_t)nE * nLD * 2;         // 8 MB
    float* sc_sum = (float*)ws;  ws += nLD * 4;
    float* ii_sum = (float*)ws;  ws += nLD * 4;
    float* os_sum = (float*)ws;  ws += nLD * 4;
    float* w2a    = (float*)ws;  ws += nLD * 4;
    float* c2     = (float*)ws;  ws += 256;
    float* scores = (float*)ws;  ws += (size_t)nBT * nL * 4;
    // aliases (lifetimes):
    unsigned short* emb_bf = (unsigned short*)vbuf;                    // dead before scan writes ybf
    unsigned short* e2sT   = (unsigned short*)vbuf + (size_t)nBT * nE; // ditto
    unsigned short* ybf    = (unsigned short*)vbuf;                    // scan out; dead after ff1
    float* hfull           = tokens;                                   // ff1 out (tokens dead after scan)
    unsigned short* hbf    = (unsigned short*)vbuf;                    // scores out (ybf dead)
    float* wbufA           = tokens;                                   // split-K partial z=0 (h dead)
    float* wbufB           = tokens + (size_t)nBT * nE;                // split-K partial z=1

    // precompute
    k_init2<<<64, 256, 0, stream>>>(recs);
    k_pack2<<<nL * 64, 256, 0, stream>>>(glu_w, wswz);
    k_wdot<<<1024, 256, 0, stream>>>(state_control, nullptr, sc_sum, nLD, nD);
    k_wdot<<<1024, 256, 0, stream>>>(input_influence, nullptr, ii_sum, nLD, nD);
    k_wdot<<<1024, 256, 0, stream>>>(output_shaper, nullptr, os_sum, nLD, nD);
    k_wdot<<<1024, 256, 0, stream>>>(ff_w2, attn_w, w2a, nLD, nE);
    k_wdot<<<2, 256, 0, stream>>>(ff_b2, attn_w, c2, nL, nE);
    k_cast<<<nBT * nE / 1024, 256, 0, stream>>>(emb, emb_bf, nBT * nE);
    k_transp<<<dim3(nLD / 32, nE / 32, 1), 256, 0, stream>>>(e2s_w, e2sT, nE, nLD, 0, 0);
    k_transp<<<dim3(nD / 32, nD / 32, nL), 256, 0, stream>>>(ff_w1, w1T, nD, nD,
                                                             (long long)nD * nD, (long long)nD * nD);
    k_transp<<<dim3(nE / 32, nLD / 32, 1), 256, 0, stream>>>(ff_w2, w2T, nLD, nE, 0, 0);

    // tokens = emb @ e2s_w + e2s_b   [4096 x 4096], K=1024  (bf16 MFMA)
    k_gemm_bf<0><<<dim3(32, 32, 1), 256, 0, stream>>>(
        emb_bf, nE, 0, e2sT, nE, 0, e2s_b, 0, tokens, nLD, 0, nBT, nLD, nE);

    // distributed recurrent scan -> ybf (y = LN_ff(LN_state(v)*os), fused)
    k_scan8<<<64, 512, 0, stream>>>(tokens, wswz, glu_b, sc_sum, ii_sum, os_sum,
                                    ln_glu_g, ln_glu_b, ln_state_g, ln_state_b,
                                    ff_ln_g, ff_ln_b, ybf, recs);

    // h = GELU(y @ ff_w1 + ff_b1), per-layer batched (bf16 MFMA) -> hfull
    k_gemm_bf<1><<<dim3(4, 32, 8), 256, 0, stream>>>(
        ybf, nLD, nD, w1T, nD, (long long)nD * nD, ff_b1, nD,
        hfull, nLD, nD, nBT, nD, nD);

    // scores; scaled h -> bf16 hbf
    k_scores<<<nBT, 256, 0, stream>>>(hfull, w2a, c2, attn_b, hbf, scores);

    // weighted = (s*h) @ W2cat, SPLIT-K=2 (z halves of K=4096) -> wbufA/B
    k_gemm_bf<0><<<dim3(8, 32, 2), 256, 0, stream>>>(
        hbf, nLD, 2048, w2T, nLD, 2048, nullptr, 0,
        wbufA, nE, (long long)nBT * nE, nBT, nE, 2048);

    // out = LN(wbufA + wbufB + sum_l s_l*ff_b2[l])
    k_final<<<nBT, 256, 0, stream>>>(wbufA, wbufB, scores, ff_b2,
                                     ln_emb_g, ln_emb_b, (float*)d_out);
}